// Round 11
// baseline (2264.179 us; speedup 1.0000x reference)
//
#include <hip/hip_runtime.h>

// offset_deform: DGCNN-style forward. B=4, N=2048, K=30.
// NUM_GRAPH loop is iteration-invariant -> compute once, pack 4x.
// R11: edgeA/statsB/poolB -> single-wave 64-thread blocks (launch_bounds(64,5)).
//      LDS 40960->8192 (vbuf[2][32][32], sred eliminated -> direct per-channel
//      double atomics). 20 independent waves/CU vs ~4 lockstepped; the R10
//      post-mortem showed the kernels are s_load-latency-stall-bound (VALUBusy
//      42%), not LDS-capacity-bound. Everything else byte-identical to R10.

#define DEV __device__ __forceinline__
DEV float lrelu(float y) { return y > 0.f ? y : 0.2f * y; }
// monotone float->unsigned map (order-preserving for all finite floats)
DEV unsigned fmap(float x) {
  unsigned u = __float_as_uint(x);
  return (u & 0x80000000u) ? ~u : (u | 0x80000000u);
}
DEV float funmap(unsigned m) {
  unsigned u = (m & 0x80000000u) ? (m & 0x7FFFFFFFu) : ~m;
  return __uint_as_float(u);
}

// ---------------- utility ----------------
__global__ void zero_kernel(float* p, int n) {
  int id = blockIdx.x * 256 + threadIdx.x;
  if (id < n) p[id] = 0.f;
}

__global__ void iminit_kernel(unsigned* maxm, unsigned* minm) {
  int id = blockIdx.x * 256 + threadIdx.x;
  if (id < 4096) { maxm[id] = 0u; minm[id] = 0xFFFFFFFFu; }
}

// input (B,3,N) -> pc (B,N,3)
__global__ void pc_kernel(const float* __restrict__ in, float* __restrict__ pc) {
  int id = blockIdx.x * 256 + threadIdx.x;
  if (id >= 4 * 3 * 2048) return;
  int n = id & 2047;
  int c = (id >> 11) % 3;
  int b = id / (3 * 2048);
  pc[((b << 11) + n) * 3 + c] = in[id];
}

// ---------------- knn: wave per query point, per-lane top-4 list ----------------
// (byte-identical to R6/R9/R10 -- known-good, absmax 0.1015625)
__global__ __launch_bounds__(256) void knn_kernel(const float* __restrict__ pts, int* __restrict__ idx_out) {
  int tid = threadIdx.x;
  int w = tid >> 6, lane = tid & 63;
  int bn = (blockIdx.x << 2) + w;
  int b = bn >> 11;
  const float* base = pts + (b << 11) * 3;
  double qx = pts[bn * 3 + 0], qy = pts[bn * 3 + 1], qz = pts[bn * 3 + 2];
  double sqn = qx * qx + qy * qy + qz * qz;
  double d[32];
#pragma unroll
  for (int i = 0; i < 32; ++i) {
    int m = lane + (i << 6);
    double px = base[m * 3 + 0], py = base[m * 3 + 1], pz = base[m * 3 + 2];
    double v = sqn - 2.0 * (qx * px + qy * py + qz * pz) + (px * px + py * py + pz * pz);
    d[i] = v;
  }
  unsigned used = 0u;
  double l0, l1, l2, l3; int p0, p1, p2, p3;
#define KNN_PASS(LV, PV)                                              \
  {                                                                   \
    double cm = 1e300; int cp = 0x7fffffff; int ci = 0;               \
    _Pragma("unroll")                                                 \
    for (int i = 0; i < 32; ++i) {                                    \
      double v = ((used >> i) & 1u) ? 1e300 : d[i];                   \
      if (v < cm) { cm = v; cp = lane + (i << 6); ci = i; }           \
    }                                                                 \
    used |= 1u << ci; LV = cm; PV = cp;                               \
  }
  KNN_PASS(l0, p0)
  KNN_PASS(l1, p1)
  KNN_PASS(l2, p2)
  KNN_PASS(l3, p3)
  int cnt = 4;
  int* out = idx_out + bn * 30;
  for (int it = 0; it < 30; ++it) {
    double gv = l0; int gp = p0;
#pragma unroll
    for (int off = 1; off < 64; off <<= 1) {
      double ov = __shfl_xor(gv, off, 64);
      int op = __shfl_xor(gp, off, 64);
      if (ov < gv || (ov == gv && op < gp)) { gv = ov; gp = op; }
    }
    if (lane == 0) out[it] = gp;
    if (lane == (gp & 63)) {          // owner: pop head
      l0 = l1; p0 = p1; l1 = l2; p1 = p2; l2 = l3; p2 = p3;
      l3 = 1e300; p3 = 0x7fffffff;
      cnt--;
      if (cnt == 0) {                 // rare: refill with true next-best
        KNN_PASS(l0, p0)
        cnt = 1;
      }
    }
  }
#undef KNN_PASS
}

// ---------------- mom6: S[6] + upper-tri M[21] of edge features ----------------
__global__ __launch_bounds__(256) void mom6_kernel(const float* __restrict__ pts, const int* __restrict__ idx,
                                                   double* __restrict__ acc) {
  __shared__ double sred[4][27];
  int tid = threadIdx.x;
  int lane = tid & 63, w = tid >> 6;
  double m[27];
#pragma unroll
  for (int i = 0; i < 27; ++i) m[i] = 0.0;
  int stride = gridDim.x << 8;
  for (int e = (blockIdx.x << 8) + tid; e < 245760; e += stride) {
    int bn = e / 30; int b = bn >> 11;
    int nb = idx[e];
    const float* cen = pts + bn * 3;
    const float* nbp = pts + ((b << 11) + nb) * 3;
    float f[6];
    f[0] = cen[0]; f[1] = cen[1]; f[2] = cen[2];
    f[3] = nbp[0] - f[0]; f[4] = nbp[1] - f[1]; f[5] = nbp[2] - f[2];
    int t = 6;
#pragma unroll
    for (int i = 0; i < 6; ++i) {
      m[i] += f[i];
#pragma unroll
      for (int j = i; j < 6; ++j) m[t++] += (double)f[i] * f[j];
    }
  }
#pragma unroll
  for (int i = 0; i < 27; ++i) {
    double v = m[i];
    v += __shfl_xor(v, 1, 64); v += __shfl_xor(v, 2, 64); v += __shfl_xor(v, 4, 64);
    v += __shfl_xor(v, 8, 64); v += __shfl_xor(v, 16, 64); v += __shfl_xor(v, 32, 64);
    m[i] = v;
  }
  if (lane == 0) {
#pragma unroll
    for (int i = 0; i < 27; ++i) sred[w][i] = m[i];
  }
  __syncthreads();
  if (tid < 27) atomicAdd(&acc[tid], sred[0][tid] + sred[1][tid] + sred[2][tid] + sred[3][tid]);
}

// finE1: per-channel mean/var from moment form  mean=w.S/E, E[x^2]=w^T M w / E
__global__ void finE1_kernel(const double* __restrict__ acc, const float* __restrict__ W,
                             const float* __restrict__ g, const float* __restrict__ bb,
                             float* __restrict__ sc) {
  int c = threadIdx.x;
  if (c >= 64) return;
  double wv[6];
#pragma unroll
  for (int i = 0; i < 6; ++i) wv[i] = W[c * 6 + i];
  double s = 0.0;
#pragma unroll
  for (int i = 0; i < 6; ++i) s += wv[i] * acc[i];
  double q = 0.0; int t = 6;
#pragma unroll
  for (int i = 0; i < 6; ++i)
#pragma unroll
    for (int j = i; j < 6; ++j) {
      double mm = acc[t++];
      q += (i == j) ? wv[i] * wv[i] * mm : 2.0 * wv[i] * wv[j] * mm;
    }
  const double E = 245760.0;
  double mean = s / E;
  double var = q / E - mean * mean;
  if (var < 0) var = 0;
  float sf = g[c] * (float)(1.0 / sqrt(var + 1e-5));
  sc[c] = sf;
  sc[64 + c] = bb[c] - (float)mean * sf;
}

// ---------------- edgeA: fused stats + pre-BN max/min pool (single-wave blocks) ----------------
// block = 1 wave = 2 points, lane&31 = k. Phase1 (per chunk of 32 ch): lane
// writes channel-q value to vbuf[pt][q][k^q] (XOR swizzle). Phase2: lane =
// (pt, ch) reads [ch][kk^ch], reduces max/min/sum/sumsq. pt0+pt1 sums via one
// shfl; channel-owner lanes (lane<32) atomicAdd directly. LDS = 8KB -> 20
// independent waves/CU. Grid MUST be 4096 (2 pts/blk).
__global__ __launch_bounds__(64, 5) void edgeA_kernel(const float* __restrict__ pts, const int* __restrict__ idx,
                                                      const float* __restrict__ W1, const float* __restrict__ sc1,
                                                      const float* __restrict__ W2,
                                                      float* __restrict__ mxout, float* __restrict__ mnout,
                                                      double* __restrict__ acc) {
  __shared__ float vbuf[2][32][32];
  int lane = threadIdx.x;
  int k = lane & 31;
  int pt = lane >> 5;
  int bn = (blockIdx.x << 1) + pt;
  int b = bn >> 11;
  bool valid = k < 30;
  int nb = idx[bn * 30 + (valid ? k : 0)];
  const float* cen = pts + bn * 3;
  const float* nbp = pts + ((b << 11) + nb) * 3;
  float cx = cen[0], cy = cen[1], cz = cen[2];
  float dx = nbp[0] - cx, dy = nbp[1] - cy, dz = nbp[2] - cz;
  float y[64];
#pragma unroll
  for (int j = 0; j < 64; ++j) {
    float x = cx * W1[j * 6 + 0] + cy * W1[j * 6 + 1] + cz * W1[j * 6 + 2]
            + dx * W1[j * 6 + 3] + dy * W1[j * 6 + 4] + dz * W1[j * 6 + 5];
    y[j] = lrelu(fmaf(x, sc1[j], sc1[64 + j]));
  }
  int ch = lane & 31, pt2 = lane >> 5;
  int bn2 = (blockIdx.x << 1) + pt2;
  double aS[4] = {0, 0, 0, 0}, aQ[4] = {0, 0, 0, 0};
#pragma unroll
  for (int cc = 0; cc < 4; ++cc) {
    for (int q = 0; q < 32; ++q) {
      int c = cc * 32 + q;
      const float* w = W2 + c * 64;
      float a0 = 0.f, a1 = 0.f, a2 = 0.f, a3 = 0.f;
#pragma unroll
      for (int j = 0; j < 64; j += 4) {
        a0 = fmaf(y[j], w[j], a0); a1 = fmaf(y[j + 1], w[j + 1], a1);
        a2 = fmaf(y[j + 2], w[j + 2], a2); a3 = fmaf(y[j + 3], w[j + 3], a3);
      }
      vbuf[pt][q][k ^ q] = (a0 + a1) + (a2 + a3);
    }
    __syncthreads();
    const float* vr = &vbuf[pt2][ch][0];
    float v0 = vr[0 ^ ch];
    float mx = v0, mn = v0, sm = v0, qq = v0 * v0;
#pragma unroll
    for (int kkk = 1; kkk < 30; ++kkk) {
      float v = vr[kkk ^ ch];
      mx = fmaxf(mx, v); mn = fminf(mn, v);
      sm += v; qq = fmaf(v, v, qq);
    }
    mxout[bn2 * 128 + cc * 32 + ch] = mx;
    mnout[bn2 * 128 + cc * 32 + ch] = mn;
    float sm1 = __shfl_xor(sm, 32, 64);
    float qq1 = __shfl_xor(qq, 32, 64);
    if (lane < 32) { aS[cc] += (double)(sm + sm1); aQ[cc] += (double)(qq + qq1); }
    __syncthreads();
  }
  if (lane < 32) {
#pragma unroll
    for (int cc = 0; cc < 4; ++cc) {
      atomicAdd(&acc[cc * 32 + lane], aS[cc]);
      atomicAdd(&acc[128 + cc * 32 + lane], aQ[cc]);
    }
  }
}

// applyA: m128[bn][c] = lrelu(s * (s>=0 ? mx : mn) + t)
__global__ void applyA_kernel(const float* __restrict__ mx, const float* __restrict__ mn,
                              const float* __restrict__ sc, float* __restrict__ m128) {
  int id = blockIdx.x * 256 + threadIdx.x;
  if (id >= 8192 * 128) return;
  int c = id & 127;
  float s = sc[c], t = sc[128 + c];
  float sel = (s >= 0.f) ? mx[id] : mn[id];
  m128[id] = lrelu(fmaf(sel, s, t));
}

// ---------------- statsB: sum/sumsq of x2 = bnlrelu(y) @ W2(64x64)^T (single-wave) ----------------
// Grid MUST be 4096. LDS 8KB.
__global__ __launch_bounds__(64, 5) void statsB_kernel(const float* __restrict__ pts, const int* __restrict__ idx,
                                                       const float* __restrict__ W1, const float* __restrict__ sc1,
                                                       const float* __restrict__ W2, double* __restrict__ acc) {
  __shared__ float vbuf[2][32][32];
  int lane = threadIdx.x;
  int k = lane & 31;
  int pt = lane >> 5;
  int bn = (blockIdx.x << 1) + pt;
  int b = bn >> 11;
  bool valid = k < 30;
  int nb = idx[bn * 30 + (valid ? k : 0)];
  const float* cen = pts + bn * 3;
  const float* nbp = pts + ((b << 11) + nb) * 3;
  float cx = cen[0], cy = cen[1], cz = cen[2];
  float dx = nbp[0] - cx, dy = nbp[1] - cy, dz = nbp[2] - cz;
  float y[64];
#pragma unroll
  for (int j = 0; j < 64; ++j) {
    float x = cx * W1[j * 6 + 0] + cy * W1[j * 6 + 1] + cz * W1[j * 6 + 2]
            + dx * W1[j * 6 + 3] + dy * W1[j * 6 + 4] + dz * W1[j * 6 + 5];
    y[j] = lrelu(fmaf(x, sc1[j], sc1[64 + j]));
  }
  int ch = lane & 31, pt2 = lane >> 5;
  double aS[2] = {0, 0}, aQ[2] = {0, 0};
#pragma unroll
  for (int cc = 0; cc < 2; ++cc) {
    for (int q = 0; q < 32; ++q) {
      int c = cc * 32 + q;
      const float* w = W2 + c * 64;
      float a0 = 0.f, a1 = 0.f, a2 = 0.f, a3 = 0.f;
#pragma unroll
      for (int j = 0; j < 64; j += 4) {
        a0 = fmaf(y[j], w[j], a0); a1 = fmaf(y[j + 1], w[j + 1], a1);
        a2 = fmaf(y[j + 2], w[j + 2], a2); a3 = fmaf(y[j + 3], w[j + 3], a3);
      }
      vbuf[pt][q][k ^ q] = (a0 + a1) + (a2 + a3);
    }
    __syncthreads();
    const float* vr = &vbuf[pt2][ch][0];
    float v0 = vr[0 ^ ch];
    float sm = v0, qq = v0 * v0;
#pragma unroll
    for (int kkk = 1; kkk < 30; ++kkk) {
      float v = vr[kkk ^ ch];
      sm += v; qq = fmaf(v, v, qq);
    }
    float sm1 = __shfl_xor(sm, 32, 64);
    float qq1 = __shfl_xor(qq, 32, 64);
    if (lane < 32) { aS[cc] += (double)(sm + sm1); aQ[cc] += (double)(qq + qq1); }
    __syncthreads();
  }
  if (lane < 32) {
#pragma unroll
    for (int cc = 0; cc < 2; ++cc) {
      atomicAdd(&acc[cc * 32 + lane], aS[cc]);
      atomicAdd(&acc[64 + cc * 32 + lane], aQ[cc]);
    }
  }
}

// ---------------- poolB: cat = [max_k v, mean_k v], v = bnlrelu(x2) (single-wave) ----------------
// Grid MUST be 4096. LDS 8KB.
__global__ __launch_bounds__(64, 5) void poolB_kernel(const float* __restrict__ pts, const int* __restrict__ idx,
                                                      const float* __restrict__ W1, const float* __restrict__ sc1,
                                                      const float* __restrict__ W2, const float* __restrict__ sc2,
                                                      float* __restrict__ cat) {
  __shared__ float vbuf[2][32][32];
  int lane = threadIdx.x;
  int k = lane & 31;
  int pt = lane >> 5;
  int bn = (blockIdx.x << 1) + pt;
  int b = bn >> 11;
  bool valid = k < 30;
  int nb = idx[bn * 30 + (valid ? k : 0)];
  const float* cen = pts + bn * 3;
  const float* nbp = pts + ((b << 11) + nb) * 3;
  float cx = cen[0], cy = cen[1], cz = cen[2];
  float dx = nbp[0] - cx, dy = nbp[1] - cy, dz = nbp[2] - cz;
  float y[64];
#pragma unroll
  for (int j = 0; j < 64; ++j) {
    float x = cx * W1[j * 6 + 0] + cy * W1[j * 6 + 1] + cz * W1[j * 6 + 2]
            + dx * W1[j * 6 + 3] + dy * W1[j * 6 + 4] + dz * W1[j * 6 + 5];
    y[j] = lrelu(fmaf(x, sc1[j], sc1[64 + j]));
  }
  int ch = lane & 31, pt2 = lane >> 5;
  int bn2 = (blockIdx.x << 1) + pt2;
#pragma unroll
  for (int cc = 0; cc < 2; ++cc) {
    for (int q = 0; q < 32; ++q) {
      int c = cc * 32 + q;
      const float* w = W2 + c * 64;
      float a0 = 0.f, a1 = 0.f, a2 = 0.f, a3 = 0.f;
#pragma unroll
      for (int j = 0; j < 64; j += 4) {
        a0 = fmaf(y[j], w[j], a0); a1 = fmaf(y[j + 1], w[j + 1], a1);
        a2 = fmaf(y[j + 2], w[j + 2], a2); a3 = fmaf(y[j + 3], w[j + 3], a3);
      }
      vbuf[pt][q][k ^ q] = (a0 + a1) + (a2 + a3);
    }
    __syncthreads();
    int c2 = cc * 32 + ch;
    float s = sc2[c2], t = sc2[64 + c2];
    const float* vr = &vbuf[pt2][ch][0];
    float v0 = lrelu(fmaf(vr[0 ^ ch], s, t));
    float mx = v0, sm = v0;
#pragma unroll
    for (int kkk = 1; kkk < 30; ++kkk) {
      float v = lrelu(fmaf(vr[kkk ^ ch], s, t));
      mx = fmaxf(mx, v); sm += v;
    }
    cat[bn2 * 128 + cc * 32 + ch] = mx;
    cat[bn2 * 128 + 64 + cc * 32 + ch] = sm * (1.f / 30.f);
    __syncthreads();
  }
}

// ---------------- xo3T[c][bn] = cat[bn][:] @ wo3[c][:] ----------------
__global__ __launch_bounds__(256) void xo3g_kernel(const float* __restrict__ cat, const float* __restrict__ W3,
                                                   float* __restrict__ xo3T) {
  int tid = threadIdx.x;
  int lane = tid & 63, cw = tid >> 6;
  int bn = (blockIdx.x << 6) + lane;
  const float* cr = cat + bn * 128;
  float a[16];
#pragma unroll
  for (int q = 0; q < 16; ++q) a[q] = 0.f;
  for (int j = 0; j < 128; ++j) {
    float v = cr[j];
#pragma unroll
    for (int q = 0; q < 16; ++q) a[q] += v * W3[(cw * 16 + q) * 128 + j];
  }
#pragma unroll
  for (int q = 0; q < 16; ++q) xo3T[(cw * 16 + q) * 8192 + bn] = a[q];
}

// ---------------- row stats: x is [C][E], one block per row ----------------
__global__ __launch_bounds__(256) void rstats_kernel(const float* __restrict__ x, int E, int C,
                                                     double* __restrict__ acc) {
  __shared__ double rd[256];
  int c = blockIdx.x, tid = threadIdx.x;
  const float* r = x + (size_t)c * E;
  double ls = 0, lq = 0;
  for (int i = tid; i < E; i += 256) { float v = r[i]; ls += v; lq += (double)v * v; }
  rd[tid] = ls; __syncthreads();
  for (int s = 128; s > 0; s >>= 1) { if (tid < s) rd[tid] += rd[tid + s]; __syncthreads(); }
  if (tid == 0) acc[c] = rd[0];
  __syncthreads();
  rd[tid] = lq; __syncthreads();
  for (int s = 128; s > 0; s >>= 1) { if (tid < s) rd[tid] += rd[tid + s]; __syncthreads(); }
  if (tid == 0) acc[C + c] = rd[0];
}

// ---------------- cmm1024: x=m128@W^T fused with {sum,sumsq,max,min} ----------------
__global__ __launch_bounds__(256) void cmm1024_kernel(const float* __restrict__ m128, const float* __restrict__ W,
                                                      double* __restrict__ acc, unsigned* __restrict__ maxm,
                                                      unsigned* __restrict__ minm) {
  __shared__ float mt[64 * 132];
  int tid = threadIdx.x;
  int lane = tid & 63;
  int b = blockIdx.x >> 8;
  int cg = (blockIdx.x >> 2) & 63;
  int ns = blockIdx.x & 3;
  int wu = __builtin_amdgcn_readfirstlane(tid >> 6);
  int cbase = cg * 16 + wu * 4;
  const float* wr = W + (size_t)cbase * 128;
  double ls[4] = {0, 0, 0, 0}, lq[4] = {0, 0, 0, 0};
  float mx[4], mn[4];
#pragma unroll
  for (int q = 0; q < 4; ++q) { mx[q] = -3.4e38f; mn[q] = 3.4e38f; }
  for (int ch = 0; ch < 8; ++ch) {
    int n0 = (ns << 9) + (ch << 6);
    __syncthreads();
    for (int i = tid; i < 2048; i += 256) {
      int r = i >> 5, jj = (i & 31) << 2;
      *(float4*)&mt[r * 132 + jj] = *(const float4*)&m128[(size_t)((b << 11) + n0 + r) * 128 + jj];
    }
    __syncthreads();
    float a[4] = {0.f, 0.f, 0.f, 0.f};
    const float* mrow = &mt[lane * 132];
#pragma unroll
    for (int j = 0; j < 128; j += 4) {
      float4 mv = *(const float4*)&mrow[j];
#pragma unroll
      for (int q = 0; q < 4; ++q) {
        const float* wq = wr + q * 128 + j;
        a[q] = fmaf(mv.x, wq[0], a[q]);
        a[q] = fmaf(mv.y, wq[1], a[q]);
        a[q] = fmaf(mv.z, wq[2], a[q]);
        a[q] = fmaf(mv.w, wq[3], a[q]);
      }
    }
#pragma unroll
    for (int q = 0; q < 4; ++q) {
      ls[q] += a[q]; lq[q] += (double)a[q] * a[q];
      mx[q] = fmaxf(mx[q], a[q]); mn[q] = fminf(mn[q], a[q]);
    }
  }
#pragma unroll
  for (int q = 0; q < 4; ++q) {
    double s = ls[q], sq = lq[q];
    float xm = mx[q], xn = mn[q];
    for (int off = 1; off < 64; off <<= 1) {
      s += __shfl_xor(s, off, 64);
      sq += __shfl_xor(sq, off, 64);
      xm = fmaxf(xm, __shfl_xor(xm, off, 64));
      xn = fminf(xn, __shfl_xor(xn, off, 64));
    }
    if (lane == 0) {
      int c = cbase + q;
      atomicAdd(&acc[c], s);
      atomicAdd(&acc[1024 + c], sq);
      atomicMax(&maxm[(b << 10) + c], fmap(xm));
      atomicMin(&minm[(b << 10) + c], fmap(xn));
    }
  }
}

// fin1024: stats -> (s,t); gmax = lrelu(s*extreme + t), extreme by sign(s)
__global__ void fin1024_kernel(const double* __restrict__ acc, const float* __restrict__ g,
                               const float* __restrict__ bb, const unsigned* __restrict__ maxm,
                               const unsigned* __restrict__ minm, float* __restrict__ gmax) {
  int c = blockIdx.x * 256 + threadIdx.x;
  if (c >= 1024) return;
  double mean = acc[c] / 8192.0;
  double var = acc[1024 + c] / 8192.0 - mean * mean;
  if (var < 0) var = 0;
  float s = g[c] * (float)(1.0 / sqrt(var + 1e-5));
  float t = bb[c] - (float)mean * s;
  for (int b = 0; b < 4; ++b) {
    float xm = (s >= 0.f) ? funmap(maxm[(b << 10) + c]) : funmap(minm[(b << 10) + c]);
    gmax[(b << 10) + c] = lrelu(fmaf(xm, s, t));
  }
}

// ---------------- fc1 -> fc2 -> transform (B,9) ----------------
__global__ __launch_bounds__(256) void fc_kernel(const float* __restrict__ gmax,
                                                 const float* __restrict__ fc1w, const float* __restrict__ fc1b,
                                                 const float* __restrict__ fc2w, const float* __restrict__ fc2b,
                                                 const float* __restrict__ tw, const float* __restrict__ tb,
                                                 float* __restrict__ transform) {
  __shared__ float net[1024];
  __shared__ float h1[512];
  __shared__ float h2[256];
  int b = blockIdx.x, tid = threadIdx.x;
  for (int i = tid; i < 1024; i += 256) net[i] = gmax[b * 1024 + i];
  __syncthreads();
  for (int o = tid; o < 512; o += 256) {
    float a = fc1b[o];
    const float* w = fc1w + o * 1024;
    for (int j = 0; j < 1024; ++j) a += net[j] * w[j];
    h1[o] = a;
  }
  __syncthreads();
  {
    int o = tid;
    float a = fc2b[o];
    const float* w = fc2w + o * 512;
    for (int j = 0; j < 512; ++j) a += h1[j] * w[j];
    h2[o] = a;
  }
  __syncthreads();
  if (tid < 9) {
    float a = 0.f;
    for (int i = 0; i < 256; ++i) a += h2[i] * tw[i * 9 + tid];
    float eye = (tid == 0 || tid == 4 || tid == 8) ? 1.f : 0.f;
    transform[b * 9 + tid] = a + eye + tb[tid];
  }
}

// ---------------- pct = pc @ transform ----------------
__global__ void pct_kernel(const float* __restrict__ pc, const float* __restrict__ T, float* __restrict__ pct) {
  int id = blockIdx.x * 256 + threadIdx.x;
  if (id >= 8192) return;
  int b = id >> 11;
  const float* t = T + b * 9;
  float x = pc[id * 3 + 0], y = pc[id * 3 + 1], z = pc[id * 3 + 2];
  pct[id * 3 + 0] = x * t[0] + y * t[3] + z * t[6];
  pct[id * 3 + 1] = x * t[1] + y * t[4] + z * t[7];
  pct[id * 3 + 2] = x * t[2] + y * t[5] + z * t[8];
}

// ---------------- dense stats, C | 256 ----------------
__global__ __launch_bounds__(256) void dstats_kernel(const float* __restrict__ x, int total, int C,
                                                     double* __restrict__ acc) {
  __shared__ double dred[256];
  int tid = threadIdx.x;
  int c = tid % C;
  double ls = 0, lq = 0;
  int stride = gridDim.x << 8;
  for (int id = (blockIdx.x << 8) + tid; id < total; id += stride) {
    float v = x[id];
    ls += v; lq += (double)v * v;
  }
  dred[tid] = ls; __syncthreads();
  if (tid < C) { double v = 0; for (int i = tid; i < 256; i += C) v += dred[i]; atomicAdd(&acc[c], v); }
  __syncthreads();
  dred[tid] = lq; __syncthreads();
  if (tid < C) { double v = 0; for (int i = tid; i < 256; i += C) v += dred[i]; atomicAdd(&acc[C + c], v); }
}

// ---------------- stats for C=3 ----------------
__global__ __launch_bounds__(256) void stats3_kernel(const float* __restrict__ x, int total, double* __restrict__ acc) {
  __shared__ double dred[256];
  int tid = threadIdx.x;
  double ls[3] = {0, 0, 0}, lq[3] = {0, 0, 0};
  int stride = gridDim.x << 8;
  for (int id = (blockIdx.x << 8) + tid; id < total; id += stride) {
    float v = x[id];
    int c = id % 3;
    ls[c] += v; lq[c] += (double)v * v;
  }
  for (int cc = 0; cc < 3; ++cc) {
    __syncthreads();
    dred[tid] = ls[cc]; __syncthreads();
    for (int s = 128; s > 0; s >>= 1) { if (tid < s) dred[tid] += dred[tid + s]; __syncthreads(); }
    if (tid == 0) atomicAdd(&acc[cc], dred[0]);
    __syncthreads();
    dred[tid] = lq[cc]; __syncthreads();
    for (int s = 128; s > 0; s >>= 1) { if (tid < s) dred[tid] += dred[tid + s]; __syncthreads(); }
    if (tid == 0) atomicAdd(&acc[3 + cc], dred[0]);
  }
}

// ---------------- finalize: acc(sum,sumsq) -> (scale, shift) ----------------
__global__ void fin_kernel(const double* __restrict__ acc, const float* __restrict__ g, const float* __restrict__ bb,
                           double cnt, int C, float* __restrict__ sc) {
  int c = blockIdx.x * 256 + threadIdx.x;
  if (c >= C) return;
  double mean = acc[c] / cnt;
  double var = acc[C + c] / cnt - mean * mean;
  if (var < 0) var = 0;
  float inv = (float)(1.0 / sqrt(var + 1e-5));
  float s = g[c] * inv;
  sc[c] = s;
  sc[C + c] = bb[c] - (float)mean * s;
}

// ---------------- IF = [pct, bnlrelu(xo3T)] (B,N,67) ----------------
__global__ void if_kernel(const float* __restrict__ pct, const float* __restrict__ xo3T, const float* __restrict__ sc3,
                          float* __restrict__ IF) {
  int id = blockIdx.x * 256 + threadIdx.x;
  if (id >= 8192 * 67) return;
  int bn = id / 67, j = id % 67;
  float v;
  if (j < 3) v = pct[bn * 3 + j];
  else { int c = j - 3; v = lrelu(fmaf(xo3T[c * 8192 + bn], sc3[c], sc3[64 + c])); }
  IF[id] = v;
}

// ---------------- xt1 = IF @ w1(3x67)^T ----------------
__global__ void xt1_kernel(const float* __restrict__ IF, const float* __restrict__ W, float* __restrict__ xt1) {
  int id = blockIdx.x * 256 + threadIdx.x;
  if (id >= 8192 * 3) return;
  int bn = id / 3, c = id % 3;
  const float* f = IF + bn * 67;
  const float* w = W + c * 67;
  float a = 0.f;
  for (int j = 0; j < 67; ++j) a += f[j] * w[j];
  xt1[id] = a;
}

__global__ void t1_kernel(const float* __restrict__ xt1, const float* __restrict__ sc, float* __restrict__ trans1) {
  int id = blockIdx.x * 256 + threadIdx.x;
  if (id >= 24576) return;
  int c = id % 3;
  trans1[id] = lrelu(fmaf(xt1[id], sc[c], sc[3 + c]));
}

// ---------------- x2 = edgefeat(IF,134) @ w2(16x134)^T, store + stats ----------------
__global__ __launch_bounds__(256) void x2_kernel(const float* __restrict__ IF, const int* __restrict__ idx,
                                                 const float* __restrict__ W, float* __restrict__ x2,
                                                 double* __restrict__ acc) {
  __shared__ float WT[134 * 16];
  __shared__ double dred[256];
  int tid = threadIdx.x;
  for (int i = tid; i < 134 * 16; i += 256) { int c = i & 15, j = i >> 4; WT[j * 16 + c] = W[c * 134 + j]; }
  __syncthreads();
  int c = tid & 15;
  double ls = 0, lq = 0;
  const int total = 245760 * 16;
  int stride = gridDim.x << 8;
  for (int id = (blockIdx.x << 8) + tid; id < total; id += stride) {
    int p = id >> 4;
    int bn = p / 30; int b = bn >> 11;
    int nb = idx[p];
    const float* cen = IF + (size_t)bn * 67;
    const float* nbp = IF + (size_t)((b << 11) + nb) * 67;
    float a = 0.f;
    for (int j = 0; j < 67; ++j) {
      float cj = cen[j];
      a += cj * WT[j * 16 + c];
      a += (nbp[j] - cj) * WT[(67 + j) * 16 + c];
    }
    x2[id] = a;
    ls += a; lq += (double)a * a;
  }
  dred[tid] = ls; __syncthreads();
  if (tid < 16) { double v = 0; for (int i = tid; i < 256; i += 16) v += dred[i]; atomicAdd(&acc[tid], v); }
  __syncthreads();
  dred[tid] = lq; __syncthreads();
  if (tid < 16) { double v = 0; for (int i = tid; i < 256; i += 16) v += dred[i]; atomicAdd(&acc[16 + tid], v); }
}

// ---------------- out4=bnlrelu(x2); nm2/ne2 over K; x3 = [nm2,ne2] @ w3^T ----------------
__global__ __launch_bounds__(256) void k5_kernel(const float* __restrict__ x2, const float* __restrict__ sc2,
                                                 const float* __restrict__ W3, float* __restrict__ nm2,
                                                 float* __restrict__ ne2, float* __restrict__ x3) {
  __shared__ float W3T[32 * 16];
  __shared__ float o5[4][32];
  int tid = threadIdx.x;
  for (int i = tid; i < 512; i += 256) { int c = i & 15, j = i >> 4; W3T[j * 16 + c] = W3[c * 32 + j]; }
  __syncthreads();
  int lane = tid & 63, w = tid >> 6;
  int bn = blockIdx.x * 4 + w;
  int c = lane & 15, kq = lane >> 4;
  float s = sc2[c], t = sc2[16 + c];
  float lm = -3.4e38f, lsm = 0.f;
  const float* xp = x2 + (size_t)bn * 30 * 16;
  for (int k = kq; k < 30; k += 4) {
    float v = lrelu(fmaf(xp[k * 16 + c], s, t));
    lm = fmaxf(lm, v); lsm += v;
  }
  float lm2 = fmaxf(lm, __shfl_down(lm, 32, 64)); lm2 = fmaxf(lm2, __shfl_down(lm2, 16, 64));
  float ls2 = lsm + __shfl_down(lsm, 32, 64); ls2 = ls2 + __shfl_down(ls2, 16, 64);
  if (lane < 16) {
    float mean = ls2 / 30.f;
    nm2[bn * 16 + c] = lm2;
    ne2[bn * 16 + c] = mean;
    o5[w][c] = lm2; o5[w][16 + c] = mean;
  }
  __syncthreads();
  if (lane < 16) {
    float a = 0.f;
#pragma unroll
    for (int j = 0; j < 32; ++j) a += o5[w][j] * W3T[j * 16 + c];
    x3[bn * 16 + c] = a;
  }
}

// ---------------- final pack (4 identical graph copies) ----------------
__global__ void out_kernel(const float* __restrict__ x3, const float* __restrict__ sc3,
                           const float* __restrict__ nm2, const float* __restrict__ ne2,
                           float* __restrict__ out) {
  int id = blockIdx.x * 256 + threadIdx.x;
  if (id >= 4 * 16 * 2048) return;
  int n = id & 2047;
  int j = (id >> 11) & 15;
  int b = id >> 15;
  int bn = (b << 11) + n;
  float v5 = lrelu(fmaf(x3[bn * 16 + j], sc3[j], sc3[16 + j]));
  float vm = nm2[bn * 16 + j];
  float ve = ne2[bn * 16 + j];
#pragma unroll
  for (int g = 0; g < 4; ++g) {
    size_t base = (size_t)(b * 64 + g * 16 + j) * 2048 + n;
    out[base] = v5;
    out[524288 + base] = vm;
    out[1048576 + base] = ve;
  }
}

extern "C" void kernel_launch(void* const* d_in, const int* in_sizes, int n_in,
                              void* d_out, int out_size, void* d_ws, size_t ws_size,
                              hipStream_t stream) {
  (void)n_in; (void)out_size; (void)ws_size;
  const float* input_image = (const float*)d_in[0];
  bool dict = (in_sizes[10] == 384);
  int I_wo1, I_go1, I_bo1, I_wo2, I_go2, I_bo2, I_wo3, I_go3, I_bo3;
  int I_w1, I_g1, I_b1, I_w2, I_g2, I_b2, I_w3, I_g3, I_b3;
  int I_fc1w, I_fc1b, I_fc2w, I_fc2b, I_tw, I_tb;
  if (dict) {
    I_wo1 = 10; I_go1 = 11; I_bo1 = 12; I_wo2 = 13; I_go2 = 14; I_bo2 = 15;
    I_wo3 = 16; I_go3 = 17; I_bo3 = 18;
    I_w1 = 19; I_g1 = 20; I_b1 = 21; I_w2 = 22; I_g2 = 23; I_b2 = 24; I_w3 = 25; I_g3 = 26; I_b3 = 27;
    I_fc1w = 28; I_fc1b = 29; I_fc2w = 30; I_fc2b = 31; I_tw = 32; I_tb = 33;
  } else {
    I_fc1w = 10; I_fc1b = 11; I_fc2w = 12; I_fc2b = 13; I_tw = 14; I_tb = 15;
    I_wo1 = 16; I_go1 = 17; I_bo1 = 18; I_wo2 = 19; I_go2 = 20; I_bo2 = 21;
    I_wo3 = 22; I_go3 = 23; I_bo3 = 24;
    I_w1 = 25; I_g1 = 26; I_b1 = 27; I_w2 = 28; I_g2 = 29; I_b2 = 30; I_w3 = 31; I_g3 = 32; I_b3 = 33;
  }
#define FIN(i) ((const float*)d_in[i])
  float* ws = (float*)d_ws;
  float* pc      = ws;
  float* pct     = ws + 24576;
  float* trans1  = ws + 49152;
  int*   idx1    = (int*)(ws + 73728);
  int*   idx2    = (int*)(ws + 319488);
  int*   idx3    = (int*)(ws + 565248);
  float* m128b   = ws + 811008;                 // 8192*128
  float* catb    = ws + 1859584;                // 8192*128
  unsigned* maxmapb = (unsigned*)(ws + 2908160);// 4096
  unsigned* minmapb = (unsigned*)(ws + 2912256);// 4096
  float* m128mx  = ws + 2916352;                // 8192*128 pre-BN max
  float* m128mn  = ws + 3964928;                // 8192*128 pre-BN min
  float* gmaxb   = ws + 10248192;
  float* transf  = ws + 10252288;
  float* xo3T    = ws + 10252352;               // 64 x 8192
  float* IFb     = ws + 10776640;
  float* xt1b    = ws + 11325504;
  float* x2b     = ws + 11350080;
  float* nm2b    = ws + 15282240;
  float* ne2b    = ws + 15413312;
  float* x3b     = ws + 15544384;
  double* acc    = (double*)(ws + 15675456);    // 4096 doubles
  float* sc      = ws + 15683648;               // 4096 floats
  const double CNT_E = 245760.0, CNT_P = 8192.0;
  const int A64 = 0, A128 = 128, A1024 = 384, AO1 = 2432, AO2 = 2560, AO3 = 2688, AT1 = 2816, A2 = 2822, A3 = 2854;

  zero_kernel<<<32, 256, 0, stream>>>((float*)acc, 8192);
  iminit_kernel<<<16, 256, 0, stream>>>(maxmapb, minmapb);
  pc_kernel<<<96, 256, 0, stream>>>(input_image, pc);
  knn_kernel<<<2048, 256, 0, stream>>>(pc, idx1);
  mom6_kernel<<<32, 256, 0, stream>>>(pc, idx1, acc + A64);
  finE1_kernel<<<1, 64, 0, stream>>>(acc + A64, FIN(1), FIN(2), FIN(3), sc + A64);
  edgeA_kernel<<<4096, 64, 0, stream>>>(pc, idx1, FIN(1), sc + A64, FIN(4), m128mx, m128mn, acc + A128);
  fin_kernel<<<1, 256, 0, stream>>>(acc + A128, FIN(5), FIN(6), CNT_E, 128, sc + A128);
  applyA_kernel<<<4096, 256, 0, stream>>>(m128mx, m128mn, sc + A128, m128b);
  cmm1024_kernel<<<1024, 256, 0, stream>>>(m128b, FIN(7), acc + A1024, maxmapb, minmapb);
  fin1024_kernel<<<4, 256, 0, stream>>>(acc + A1024, FIN(8), FIN(9), maxmapb, minmapb, gmaxb);
  fc_kernel<<<4, 256, 0, stream>>>(gmaxb, FIN(I_fc1w), FIN(I_fc1b), FIN(I_fc2w), FIN(I_fc2b), FIN(I_tw), FIN(I_tb), transf);
  pct_kernel<<<32, 256, 0, stream>>>(pc, transf, pct);
  knn_kernel<<<2048, 256, 0, stream>>>(pct, idx2);
  mom6_kernel<<<32, 256, 0, stream>>>(pct, idx2, acc + AO1);
  finE1_kernel<<<1, 64, 0, stream>>>(acc + AO1, FIN(I_wo1), FIN(I_go1), FIN(I_bo1), sc + AO1);
  statsB_kernel<<<4096, 64, 0, stream>>>(pct, idx2, FIN(I_wo1), sc + AO1, FIN(I_wo2), acc + AO2);
  fin_kernel<<<1, 256, 0, stream>>>(acc + AO2, FIN(I_go2), FIN(I_bo2), CNT_E, 64, sc + AO2);
  poolB_kernel<<<4096, 64, 0, stream>>>(pct, idx2, FIN(I_wo1), sc + AO1, FIN(I_wo2), sc + AO2, catb);
  xo3g_kernel<<<128, 256, 0, stream>>>(catb, FIN(I_wo3), xo3T);
  rstats_kernel<<<64, 256, 0, stream>>>(xo3T, 8192, 64, acc + AO3);
  fin_kernel<<<1, 256, 0, stream>>>(acc + AO3, FIN(I_go3), FIN(I_bo3), CNT_P, 64, sc + AO3);
  if_kernel<<<2144, 256, 0, stream>>>(pct, xo3T, sc + AO3, IFb);
  xt1_kernel<<<96, 256, 0, stream>>>(IFb, FIN(I_w1), xt1b);
  stats3_kernel<<<32, 256, 0, stream>>>(xt1b, 24576, acc + AT1);
  fin_kernel<<<1, 256, 0, stream>>>(acc + AT1, FIN(I_g1), FIN(I_b1), CNT_P, 3, sc + AT1);
  t1_kernel<<<96, 256, 0, stream>>>(xt1b, sc + AT1, trans1);
  knn_kernel<<<2048, 256, 0, stream>>>(trans1, idx3);
  x2_kernel<<<512, 256, 0, stream>>>(IFb, idx3, FIN(I_w2), x2b, acc + A2);
  fin_kernel<<<1, 256, 0, stream>>>(acc + A2, FIN(I_g2), FIN(I_b2), CNT_E, 16, sc + A2);
  k5_kernel<<<2048, 256, 0, stream>>>(x2b, sc + A2, FIN(I_w3), nm2b, ne2b, x3b);
  dstats_kernel<<<256, 256, 0, stream>>>(x3b, 131072, 16, acc + A3);
  fin_kernel<<<1, 256, 0, stream>>>(acc + A3, FIN(I_g3), FIN(I_b3), CNT_P, 16, sc + A3);
  out_kernel<<<512, 256, 0, stream>>>(x3b, sc + A3, nm2b, ne2b, (float*)d_out);
#undef FIN
}

// Round 12
// 1261.928 us; speedup vs baseline: 1.7942x; 1.7942x over previous
//
#include <hip/hip_runtime.h>

// offset_deform: DGCNN-style forward. B=4, N=2048, K=30.
// NUM_GRAPH loop is iteration-invariant -> compute once, pack 4x.
// R12: R11 with ONE fix -- launch_bounds(64,5) -> launch_bounds(64,2) on
//      edgeA/statsB/poolB. R11's (64,5) capped VGPR at 48 -> y[64] spilled to
//      scratch -> 1.75GB FETCH, 690us. (64,2) allows 256 VGPR; working set
//      ~100 fits. Code otherwise byte-identical to R11 (which was numerically
//      correct: absmax 0.1015625).

#define DEV __device__ __forceinline__
DEV float lrelu(float y) { return y > 0.f ? y : 0.2f * y; }
// monotone float->unsigned map (order-preserving for all finite floats)
DEV unsigned fmap(float x) {
  unsigned u = __float_as_uint(x);
  return (u & 0x80000000u) ? ~u : (u | 0x80000000u);
}
DEV float funmap(unsigned m) {
  unsigned u = (m & 0x80000000u) ? (m & 0x7FFFFFFFu) : ~m;
  return __uint_as_float(u);
}

// ---------------- utility ----------------
__global__ void zero_kernel(float* p, int n) {
  int id = blockIdx.x * 256 + threadIdx.x;
  if (id < n) p[id] = 0.f;
}

__global__ void iminit_kernel(unsigned* maxm, unsigned* minm) {
  int id = blockIdx.x * 256 + threadIdx.x;
  if (id < 4096) { maxm[id] = 0u; minm[id] = 0xFFFFFFFFu; }
}

// input (B,3,N) -> pc (B,N,3)
__global__ void pc_kernel(const float* __restrict__ in, float* __restrict__ pc) {
  int id = blockIdx.x * 256 + threadIdx.x;
  if (id >= 4 * 3 * 2048) return;
  int n = id & 2047;
  int c = (id >> 11) % 3;
  int b = id / (3 * 2048);
  pc[((b << 11) + n) * 3 + c] = in[id];
}

// ---------------- knn: wave per query point, per-lane top-4 list ----------------
// (byte-identical to R6/R9/R10 -- known-good, absmax 0.1015625)
__global__ __launch_bounds__(256) void knn_kernel(const float* __restrict__ pts, int* __restrict__ idx_out) {
  int tid = threadIdx.x;
  int w = tid >> 6, lane = tid & 63;
  int bn = (blockIdx.x << 2) + w;
  int b = bn >> 11;
  const float* base = pts + (b << 11) * 3;
  double qx = pts[bn * 3 + 0], qy = pts[bn * 3 + 1], qz = pts[bn * 3 + 2];
  double sqn = qx * qx + qy * qy + qz * qz;
  double d[32];
#pragma unroll
  for (int i = 0; i < 32; ++i) {
    int m = lane + (i << 6);
    double px = base[m * 3 + 0], py = base[m * 3 + 1], pz = base[m * 3 + 2];
    double v = sqn - 2.0 * (qx * px + qy * py + qz * pz) + (px * px + py * py + pz * pz);
    d[i] = v;
  }
  unsigned used = 0u;
  double l0, l1, l2, l3; int p0, p1, p2, p3;
#define KNN_PASS(LV, PV)                                              \
  {                                                                   \
    double cm = 1e300; int cp = 0x7fffffff; int ci = 0;               \
    _Pragma("unroll")                                                 \
    for (int i = 0; i < 32; ++i) {                                    \
      double v = ((used >> i) & 1u) ? 1e300 : d[i];                   \
      if (v < cm) { cm = v; cp = lane + (i << 6); ci = i; }           \
    }                                                                 \
    used |= 1u << ci; LV = cm; PV = cp;                               \
  }
  KNN_PASS(l0, p0)
  KNN_PASS(l1, p1)
  KNN_PASS(l2, p2)
  KNN_PASS(l3, p3)
  int cnt = 4;
  int* out = idx_out + bn * 30;
  for (int it = 0; it < 30; ++it) {
    double gv = l0; int gp = p0;
#pragma unroll
    for (int off = 1; off < 64; off <<= 1) {
      double ov = __shfl_xor(gv, off, 64);
      int op = __shfl_xor(gp, off, 64);
      if (ov < gv || (ov == gv && op < gp)) { gv = ov; gp = op; }
    }
    if (lane == 0) out[it] = gp;
    if (lane == (gp & 63)) {          // owner: pop head
      l0 = l1; p0 = p1; l1 = l2; p1 = p2; l2 = l3; p2 = p3;
      l3 = 1e300; p3 = 0x7fffffff;
      cnt--;
      if (cnt == 0) {                 // rare: refill with true next-best
        KNN_PASS(l0, p0)
        cnt = 1;
      }
    }
  }
#undef KNN_PASS
}

// ---------------- mom6: S[6] + upper-tri M[21] of edge features ----------------
__global__ __launch_bounds__(256) void mom6_kernel(const float* __restrict__ pts, const int* __restrict__ idx,
                                                   double* __restrict__ acc) {
  __shared__ double sred[4][27];
  int tid = threadIdx.x;
  int lane = tid & 63, w = tid >> 6;
  double m[27];
#pragma unroll
  for (int i = 0; i < 27; ++i) m[i] = 0.0;
  int stride = gridDim.x << 8;
  for (int e = (blockIdx.x << 8) + tid; e < 245760; e += stride) {
    int bn = e / 30; int b = bn >> 11;
    int nb = idx[e];
    const float* cen = pts + bn * 3;
    const float* nbp = pts + ((b << 11) + nb) * 3;
    float f[6];
    f[0] = cen[0]; f[1] = cen[1]; f[2] = cen[2];
    f[3] = nbp[0] - f[0]; f[4] = nbp[1] - f[1]; f[5] = nbp[2] - f[2];
    int t = 6;
#pragma unroll
    for (int i = 0; i < 6; ++i) {
      m[i] += f[i];
#pragma unroll
      for (int j = i; j < 6; ++j) m[t++] += (double)f[i] * f[j];
    }
  }
#pragma unroll
  for (int i = 0; i < 27; ++i) {
    double v = m[i];
    v += __shfl_xor(v, 1, 64); v += __shfl_xor(v, 2, 64); v += __shfl_xor(v, 4, 64);
    v += __shfl_xor(v, 8, 64); v += __shfl_xor(v, 16, 64); v += __shfl_xor(v, 32, 64);
    m[i] = v;
  }
  if (lane == 0) {
#pragma unroll
    for (int i = 0; i < 27; ++i) sred[w][i] = m[i];
  }
  __syncthreads();
  if (tid < 27) atomicAdd(&acc[tid], sred[0][tid] + sred[1][tid] + sred[2][tid] + sred[3][tid]);
}

// finE1: per-channel mean/var from moment form  mean=w.S/E, E[x^2]=w^T M w / E
__global__ void finE1_kernel(const double* __restrict__ acc, const float* __restrict__ W,
                             const float* __restrict__ g, const float* __restrict__ bb,
                             float* __restrict__ sc) {
  int c = threadIdx.x;
  if (c >= 64) return;
  double wv[6];
#pragma unroll
  for (int i = 0; i < 6; ++i) wv[i] = W[c * 6 + i];
  double s = 0.0;
#pragma unroll
  for (int i = 0; i < 6; ++i) s += wv[i] * acc[i];
  double q = 0.0; int t = 6;
#pragma unroll
  for (int i = 0; i < 6; ++i)
#pragma unroll
    for (int j = i; j < 6; ++j) {
      double mm = acc[t++];
      q += (i == j) ? wv[i] * wv[i] * mm : 2.0 * wv[i] * wv[j] * mm;
    }
  const double E = 245760.0;
  double mean = s / E;
  double var = q / E - mean * mean;
  if (var < 0) var = 0;
  float sf = g[c] * (float)(1.0 / sqrt(var + 1e-5));
  sc[c] = sf;
  sc[64 + c] = bb[c] - (float)mean * sf;
}

// ---------------- edgeA: fused stats + pre-BN max/min pool (single-wave blocks) ----------------
// block = 1 wave = 2 points, lane&31 = k. Phase1 (per chunk of 32 ch): lane
// writes channel-q value to vbuf[pt][q][k^q] (XOR swizzle). Phase2: lane =
// (pt, ch) reads [ch][kk^ch], reduces max/min/sum/sumsq. pt0+pt1 sums via one
// shfl; channel-owner lanes (lane<32) atomicAdd directly. LDS = 8KB.
// launch_bounds(64,2): VGPR cap 256 -- y[64] must stay in registers.
// Grid MUST be 4096 (2 pts/blk).
__global__ __launch_bounds__(64, 2) void edgeA_kernel(const float* __restrict__ pts, const int* __restrict__ idx,
                                                      const float* __restrict__ W1, const float* __restrict__ sc1,
                                                      const float* __restrict__ W2,
                                                      float* __restrict__ mxout, float* __restrict__ mnout,
                                                      double* __restrict__ acc) {
  __shared__ float vbuf[2][32][32];
  int lane = threadIdx.x;
  int k = lane & 31;
  int pt = lane >> 5;
  int bn = (blockIdx.x << 1) + pt;
  int b = bn >> 11;
  bool valid = k < 30;
  int nb = idx[bn * 30 + (valid ? k : 0)];
  const float* cen = pts + bn * 3;
  const float* nbp = pts + ((b << 11) + nb) * 3;
  float cx = cen[0], cy = cen[1], cz = cen[2];
  float dx = nbp[0] - cx, dy = nbp[1] - cy, dz = nbp[2] - cz;
  float y[64];
#pragma unroll
  for (int j = 0; j < 64; ++j) {
    float x = cx * W1[j * 6 + 0] + cy * W1[j * 6 + 1] + cz * W1[j * 6 + 2]
            + dx * W1[j * 6 + 3] + dy * W1[j * 6 + 4] + dz * W1[j * 6 + 5];
    y[j] = lrelu(fmaf(x, sc1[j], sc1[64 + j]));
  }
  int ch = lane & 31, pt2 = lane >> 5;
  int bn2 = (blockIdx.x << 1) + pt2;
  double aS[4] = {0, 0, 0, 0}, aQ[4] = {0, 0, 0, 0};
#pragma unroll
  for (int cc = 0; cc < 4; ++cc) {
    for (int q = 0; q < 32; ++q) {
      int c = cc * 32 + q;
      const float* w = W2 + c * 64;
      float a0 = 0.f, a1 = 0.f, a2 = 0.f, a3 = 0.f;
#pragma unroll
      for (int j = 0; j < 64; j += 4) {
        a0 = fmaf(y[j], w[j], a0); a1 = fmaf(y[j + 1], w[j + 1], a1);
        a2 = fmaf(y[j + 2], w[j + 2], a2); a3 = fmaf(y[j + 3], w[j + 3], a3);
      }
      vbuf[pt][q][k ^ q] = (a0 + a1) + (a2 + a3);
    }
    __syncthreads();
    const float* vr = &vbuf[pt2][ch][0];
    float v0 = vr[0 ^ ch];
    float mx = v0, mn = v0, sm = v0, qq = v0 * v0;
#pragma unroll
    for (int kkk = 1; kkk < 30; ++kkk) {
      float v = vr[kkk ^ ch];
      mx = fmaxf(mx, v); mn = fminf(mn, v);
      sm += v; qq = fmaf(v, v, qq);
    }
    mxout[bn2 * 128 + cc * 32 + ch] = mx;
    mnout[bn2 * 128 + cc * 32 + ch] = mn;
    float sm1 = __shfl_xor(sm, 32, 64);
    float qq1 = __shfl_xor(qq, 32, 64);
    if (lane < 32) { aS[cc] += (double)(sm + sm1); aQ[cc] += (double)(qq + qq1); }
    __syncthreads();
  }
  if (lane < 32) {
#pragma unroll
    for (int cc = 0; cc < 4; ++cc) {
      atomicAdd(&acc[cc * 32 + lane], aS[cc]);
      atomicAdd(&acc[128 + cc * 32 + lane], aQ[cc]);
    }
  }
}

// applyA: m128[bn][c] = lrelu(s * (s>=0 ? mx : mn) + t)
__global__ void applyA_kernel(const float* __restrict__ mx, const float* __restrict__ mn,
                              const float* __restrict__ sc, float* __restrict__ m128) {
  int id = blockIdx.x * 256 + threadIdx.x;
  if (id >= 8192 * 128) return;
  int c = id & 127;
  float s = sc[c], t = sc[128 + c];
  float sel = (s >= 0.f) ? mx[id] : mn[id];
  m128[id] = lrelu(fmaf(sel, s, t));
}

// ---------------- statsB: sum/sumsq of x2 = bnlrelu(y) @ W2(64x64)^T (single-wave) ----------------
// Grid MUST be 4096. LDS 8KB. launch_bounds(64,2).
__global__ __launch_bounds__(64, 2) void statsB_kernel(const float* __restrict__ pts, const int* __restrict__ idx,
                                                       const float* __restrict__ W1, const float* __restrict__ sc1,
                                                       const float* __restrict__ W2, double* __restrict__ acc) {
  __shared__ float vbuf[2][32][32];
  int lane = threadIdx.x;
  int k = lane & 31;
  int pt = lane >> 5;
  int bn = (blockIdx.x << 1) + pt;
  int b = bn >> 11;
  bool valid = k < 30;
  int nb = idx[bn * 30 + (valid ? k : 0)];
  const float* cen = pts + bn * 3;
  const float* nbp = pts + ((b << 11) + nb) * 3;
  float cx = cen[0], cy = cen[1], cz = cen[2];
  float dx = nbp[0] - cx, dy = nbp[1] - cy, dz = nbp[2] - cz;
  float y[64];
#pragma unroll
  for (int j = 0; j < 64; ++j) {
    float x = cx * W1[j * 6 + 0] + cy * W1[j * 6 + 1] + cz * W1[j * 6 + 2]
            + dx * W1[j * 6 + 3] + dy * W1[j * 6 + 4] + dz * W1[j * 6 + 5];
    y[j] = lrelu(fmaf(x, sc1[j], sc1[64 + j]));
  }
  int ch = lane & 31, pt2 = lane >> 5;
  double aS[2] = {0, 0}, aQ[2] = {0, 0};
#pragma unroll
  for (int cc = 0; cc < 2; ++cc) {
    for (int q = 0; q < 32; ++q) {
      int c = cc * 32 + q;
      const float* w = W2 + c * 64;
      float a0 = 0.f, a1 = 0.f, a2 = 0.f, a3 = 0.f;
#pragma unroll
      for (int j = 0; j < 64; j += 4) {
        a0 = fmaf(y[j], w[j], a0); a1 = fmaf(y[j + 1], w[j + 1], a1);
        a2 = fmaf(y[j + 2], w[j + 2], a2); a3 = fmaf(y[j + 3], w[j + 3], a3);
      }
      vbuf[pt][q][k ^ q] = (a0 + a1) + (a2 + a3);
    }
    __syncthreads();
    const float* vr = &vbuf[pt2][ch][0];
    float v0 = vr[0 ^ ch];
    float sm = v0, qq = v0 * v0;
#pragma unroll
    for (int kkk = 1; kkk < 30; ++kkk) {
      float v = vr[kkk ^ ch];
      sm += v; qq = fmaf(v, v, qq);
    }
    float sm1 = __shfl_xor(sm, 32, 64);
    float qq1 = __shfl_xor(qq, 32, 64);
    if (lane < 32) { aS[cc] += (double)(sm + sm1); aQ[cc] += (double)(qq + qq1); }
    __syncthreads();
  }
  if (lane < 32) {
#pragma unroll
    for (int cc = 0; cc < 2; ++cc) {
      atomicAdd(&acc[cc * 32 + lane], aS[cc]);
      atomicAdd(&acc[64 + cc * 32 + lane], aQ[cc]);
    }
  }
}

// ---------------- poolB: cat = [max_k v, mean_k v], v = bnlrelu(x2) (single-wave) ----------------
// Grid MUST be 4096. LDS 8KB. launch_bounds(64,2).
__global__ __launch_bounds__(64, 2) void poolB_kernel(const float* __restrict__ pts, const int* __restrict__ idx,
                                                      const float* __restrict__ W1, const float* __restrict__ sc1,
                                                      const float* __restrict__ W2, const float* __restrict__ sc2,
                                                      float* __restrict__ cat) {
  __shared__ float vbuf[2][32][32];
  int lane = threadIdx.x;
  int k = lane & 31;
  int pt = lane >> 5;
  int bn = (blockIdx.x << 1) + pt;
  int b = bn >> 11;
  bool valid = k < 30;
  int nb = idx[bn * 30 + (valid ? k : 0)];
  const float* cen = pts + bn * 3;
  const float* nbp = pts + ((b << 11) + nb) * 3;
  float cx = cen[0], cy = cen[1], cz = cen[2];
  float dx = nbp[0] - cx, dy = nbp[1] - cy, dz = nbp[2] - cz;
  float y[64];
#pragma unroll
  for (int j = 0; j < 64; ++j) {
    float x = cx * W1[j * 6 + 0] + cy * W1[j * 6 + 1] + cz * W1[j * 6 + 2]
            + dx * W1[j * 6 + 3] + dy * W1[j * 6 + 4] + dz * W1[j * 6 + 5];
    y[j] = lrelu(fmaf(x, sc1[j], sc1[64 + j]));
  }
  int ch = lane & 31, pt2 = lane >> 5;
  int bn2 = (blockIdx.x << 1) + pt2;
#pragma unroll
  for (int cc = 0; cc < 2; ++cc) {
    for (int q = 0; q < 32; ++q) {
      int c = cc * 32 + q;
      const float* w = W2 + c * 64;
      float a0 = 0.f, a1 = 0.f, a2 = 0.f, a3 = 0.f;
#pragma unroll
      for (int j = 0; j < 64; j += 4) {
        a0 = fmaf(y[j], w[j], a0); a1 = fmaf(y[j + 1], w[j + 1], a1);
        a2 = fmaf(y[j + 2], w[j + 2], a2); a3 = fmaf(y[j + 3], w[j + 3], a3);
      }
      vbuf[pt][q][k ^ q] = (a0 + a1) + (a2 + a3);
    }
    __syncthreads();
    int c2 = cc * 32 + ch;
    float s = sc2[c2], t = sc2[64 + c2];
    const float* vr = &vbuf[pt2][ch][0];
    float v0 = lrelu(fmaf(vr[0 ^ ch], s, t));
    float mx = v0, sm = v0;
#pragma unroll
    for (int kkk = 1; kkk < 30; ++kkk) {
      float v = lrelu(fmaf(vr[kkk ^ ch], s, t));
      mx = fmaxf(mx, v); sm += v;
    }
    cat[bn2 * 128 + cc * 32 + ch] = mx;
    cat[bn2 * 128 + 64 + cc * 32 + ch] = sm * (1.f / 30.f);
    __syncthreads();
  }
}

// ---------------- xo3T[c][bn] = cat[bn][:] @ wo3[c][:] ----------------
__global__ __launch_bounds__(256) void xo3g_kernel(const float* __restrict__ cat, const float* __restrict__ W3,
                                                   float* __restrict__ xo3T) {
  int tid = threadIdx.x;
  int lane = tid & 63, cw = tid >> 6;
  int bn = (blockIdx.x << 6) + lane;
  const float* cr = cat + bn * 128;
  float a[16];
#pragma unroll
  for (int q = 0; q < 16; ++q) a[q] = 0.f;
  for (int j = 0; j < 128; ++j) {
    float v = cr[j];
#pragma unroll
    for (int q = 0; q < 16; ++q) a[q] += v * W3[(cw * 16 + q) * 128 + j];
  }
#pragma unroll
  for (int q = 0; q < 16; ++q) xo3T[(cw * 16 + q) * 8192 + bn] = a[q];
}

// ---------------- row stats: x is [C][E], one block per row ----------------
__global__ __launch_bounds__(256) void rstats_kernel(const float* __restrict__ x, int E, int C,
                                                     double* __restrict__ acc) {
  __shared__ double rd[256];
  int c = blockIdx.x, tid = threadIdx.x;
  const float* r = x + (size_t)c * E;
  double ls = 0, lq = 0;
  for (int i = tid; i < E; i += 256) { float v = r[i]; ls += v; lq += (double)v * v; }
  rd[tid] = ls; __syncthreads();
  for (int s = 128; s > 0; s >>= 1) { if (tid < s) rd[tid] += rd[tid + s]; __syncthreads(); }
  if (tid == 0) acc[c] = rd[0];
  __syncthreads();
  rd[tid] = lq; __syncthreads();
  for (int s = 128; s > 0; s >>= 1) { if (tid < s) rd[tid] += rd[tid + s]; __syncthreads(); }
  if (tid == 0) acc[C + c] = rd[0];
}

// ---------------- cmm1024: x=m128@W^T fused with {sum,sumsq,max,min} ----------------
__global__ __launch_bounds__(256) void cmm1024_kernel(const float* __restrict__ m128, const float* __restrict__ W,
                                                      double* __restrict__ acc, unsigned* __restrict__ maxm,
                                                      unsigned* __restrict__ minm) {
  __shared__ float mt[64 * 132];
  int tid = threadIdx.x;
  int lane = tid & 63;
  int b = blockIdx.x >> 8;
  int cg = (blockIdx.x >> 2) & 63;
  int ns = blockIdx.x & 3;
  int wu = __builtin_amdgcn_readfirstlane(tid >> 6);
  int cbase = cg * 16 + wu * 4;
  const float* wr = W + (size_t)cbase * 128;
  double ls[4] = {0, 0, 0, 0}, lq[4] = {0, 0, 0, 0};
  float mx[4], mn[4];
#pragma unroll
  for (int q = 0; q < 4; ++q) { mx[q] = -3.4e38f; mn[q] = 3.4e38f; }
  for (int ch = 0; ch < 8; ++ch) {
    int n0 = (ns << 9) + (ch << 6);
    __syncthreads();
    for (int i = tid; i < 2048; i += 256) {
      int r = i >> 5, jj = (i & 31) << 2;
      *(float4*)&mt[r * 132 + jj] = *(const float4*)&m128[(size_t)((b << 11) + n0 + r) * 128 + jj];
    }
    __syncthreads();
    float a[4] = {0.f, 0.f, 0.f, 0.f};
    const float* mrow = &mt[lane * 132];
#pragma unroll
    for (int j = 0; j < 128; j += 4) {
      float4 mv = *(const float4*)&mrow[j];
#pragma unroll
      for (int q = 0; q < 4; ++q) {
        const float* wq = wr + q * 128 + j;
        a[q] = fmaf(mv.x, wq[0], a[q]);
        a[q] = fmaf(mv.y, wq[1], a[q]);
        a[q] = fmaf(mv.z, wq[2], a[q]);
        a[q] = fmaf(mv.w, wq[3], a[q]);
      }
    }
#pragma unroll
    for (int q = 0; q < 4; ++q) {
      ls[q] += a[q]; lq[q] += (double)a[q] * a[q];
      mx[q] = fmaxf(mx[q], a[q]); mn[q] = fminf(mn[q], a[q]);
    }
  }
#pragma unroll
  for (int q = 0; q < 4; ++q) {
    double s = ls[q], sq = lq[q];
    float xm = mx[q], xn = mn[q];
    for (int off = 1; off < 64; off <<= 1) {
      s += __shfl_xor(s, off, 64);
      sq += __shfl_xor(sq, off, 64);
      xm = fmaxf(xm, __shfl_xor(xm, off, 64));
      xn = fminf(xn, __shfl_xor(xn, off, 64));
    }
    if (lane == 0) {
      int c = cbase + q;
      atomicAdd(&acc[c], s);
      atomicAdd(&acc[1024 + c], sq);
      atomicMax(&maxm[(b << 10) + c], fmap(xm));
      atomicMin(&minm[(b << 10) + c], fmap(xn));
    }
  }
}

// fin1024: stats -> (s,t); gmax = lrelu(s*extreme + t), extreme by sign(s)
__global__ void fin1024_kernel(const double* __restrict__ acc, const float* __restrict__ g,
                               const float* __restrict__ bb, const unsigned* __restrict__ maxm,
                               const unsigned* __restrict__ minm, float* __restrict__ gmax) {
  int c = blockIdx.x * 256 + threadIdx.x;
  if (c >= 1024) return;
  double mean = acc[c] / 8192.0;
  double var = acc[1024 + c] / 8192.0 - mean * mean;
  if (var < 0) var = 0;
  float s = g[c] * (float)(1.0 / sqrt(var + 1e-5));
  float t = bb[c] - (float)mean * s;
  for (int b = 0; b < 4; ++b) {
    float xm = (s >= 0.f) ? funmap(maxm[(b << 10) + c]) : funmap(minm[(b << 10) + c]);
    gmax[(b << 10) + c] = lrelu(fmaf(xm, s, t));
  }
}

// ---------------- fc1 -> fc2 -> transform (B,9) ----------------
__global__ __launch_bounds__(256) void fc_kernel(const float* __restrict__ gmax,
                                                 const float* __restrict__ fc1w, const float* __restrict__ fc1b,
                                                 const float* __restrict__ fc2w, const float* __restrict__ fc2b,
                                                 const float* __restrict__ tw, const float* __restrict__ tb,
                                                 float* __restrict__ transform) {
  __shared__ float net[1024];
  __shared__ float h1[512];
  __shared__ float h2[256];
  int b = blockIdx.x, tid = threadIdx.x;
  for (int i = tid; i < 1024; i += 256) net[i] = gmax[b * 1024 + i];
  __syncthreads();
  for (int o = tid; o < 512; o += 256) {
    float a = fc1b[o];
    const float* w = fc1w + o * 1024;
    for (int j = 0; j < 1024; ++j) a += net[j] * w[j];
    h1[o] = a;
  }
  __syncthreads();
  {
    int o = tid;
    float a = fc2b[o];
    const float* w = fc2w + o * 512;
    for (int j = 0; j < 512; ++j) a += h1[j] * w[j];
    h2[o] = a;
  }
  __syncthreads();
  if (tid < 9) {
    float a = 0.f;
    for (int i = 0; i < 256; ++i) a += h2[i] * tw[i * 9 + tid];
    float eye = (tid == 0 || tid == 4 || tid == 8) ? 1.f : 0.f;
    transform[b * 9 + tid] = a + eye + tb[tid];
  }
}

// ---------------- pct = pc @ transform ----------------
__global__ void pct_kernel(const float* __restrict__ pc, const float* __restrict__ T, float* __restrict__ pct) {
  int id = blockIdx.x * 256 + threadIdx.x;
  if (id >= 8192) return;
  int b = id >> 11;
  const float* t = T + b * 9;
  float x = pc[id * 3 + 0], y = pc[id * 3 + 1], z = pc[id * 3 + 2];
  pct[id * 3 + 0] = x * t[0] + y * t[3] + z * t[6];
  pct[id * 3 + 1] = x * t[1] + y * t[4] + z * t[7];
  pct[id * 3 + 2] = x * t[2] + y * t[5] + z * t[8];
}

// ---------------- dense stats, C | 256 ----------------
__global__ __launch_bounds__(256) void dstats_kernel(const float* __restrict__ x, int total, int C,
                                                     double* __restrict__ acc) {
  __shared__ double dred[256];
  int tid = threadIdx.x;
  int c = tid % C;
  double ls = 0, lq = 0;
  int stride = gridDim.x << 8;
  for (int id = (blockIdx.x << 8) + tid; id < total; id += stride) {
    float v = x[id];
    ls += v; lq += (double)v * v;
  }
  dred[tid] = ls; __syncthreads();
  if (tid < C) { double v = 0; for (int i = tid; i < 256; i += C) v += dred[i]; atomicAdd(&acc[c], v); }
  __syncthreads();
  dred[tid] = lq; __syncthreads();
  if (tid < C) { double v = 0; for (int i = tid; i < 256; i += C) v += dred[i]; atomicAdd(&acc[C + c], v); }
}

// ---------------- stats for C=3 ----------------
__global__ __launch_bounds__(256) void stats3_kernel(const float* __restrict__ x, int total, double* __restrict__ acc) {
  __shared__ double dred[256];
  int tid = threadIdx.x;
  double ls[3] = {0, 0, 0}, lq[3] = {0, 0, 0};
  int stride = gridDim.x << 8;
  for (int id = (blockIdx.x << 8) + tid; id < total; id += stride) {
    float v = x[id];
    int c = id % 3;
    ls[c] += v; lq[c] += (double)v * v;
  }
  for (int cc = 0; cc < 3; ++cc) {
    __syncthreads();
    dred[tid] = ls[cc]; __syncthreads();
    for (int s = 128; s > 0; s >>= 1) { if (tid < s) dred[tid] += dred[tid + s]; __syncthreads(); }
    if (tid == 0) atomicAdd(&acc[cc], dred[0]);
    __syncthreads();
    dred[tid] = lq[cc]; __syncthreads();
    for (int s = 128; s > 0; s >>= 1) { if (tid < s) dred[tid] += dred[tid + s]; __syncthreads(); }
    if (tid == 0) atomicAdd(&acc[3 + cc], dred[0]);
  }
}

// ---------------- finalize: acc(sum,sumsq) -> (scale, shift) ----------------
__global__ void fin_kernel(const double* __restrict__ acc, const float* __restrict__ g, const float* __restrict__ bb,
                           double cnt, int C, float* __restrict__ sc) {
  int c = blockIdx.x * 256 + threadIdx.x;
  if (c >= C) return;
  double mean = acc[c] / cnt;
  double var = acc[C + c] / cnt - mean * mean;
  if (var < 0) var = 0;
  float inv = (float)(1.0 / sqrt(var + 1e-5));
  float s = g[c] * inv;
  sc[c] = s;
  sc[C + c] = bb[c] - (float)mean * s;
}

// ---------------- IF = [pct, bnlrelu(xo3T)] (B,N,67) ----------------
__global__ void if_kernel(const float* __restrict__ pct, const float* __restrict__ xo3T, const float* __restrict__ sc3,
                          float* __restrict__ IF) {
  int id = blockIdx.x * 256 + threadIdx.x;
  if (id >= 8192 * 67) return;
  int bn = id / 67, j = id % 67;
  float v;
  if (j < 3) v = pct[bn * 3 + j];
  else { int c = j - 3; v = lrelu(fmaf(xo3T[c * 8192 + bn], sc3[c], sc3[64 + c])); }
  IF[id] = v;
}

// ---------------- xt1 = IF @ w1(3x67)^T ----------------
__global__ void xt1_kernel(const float* __restrict__ IF, const float* __restrict__ W, float* __restrict__ xt1) {
  int id = blockIdx.x * 256 + threadIdx.x;
  if (id >= 8192 * 3) return;
  int bn = id / 3, c = id % 3;
  const float* f = IF + bn * 67;
  const float* w = W + c * 67;
  float a = 0.f;
  for (int j = 0; j < 67; ++j) a += f[j] * w[j];
  xt1[id] = a;
}

__global__ void t1_kernel(const float* __restrict__ xt1, const float* __restrict__ sc, float* __restrict__ trans1) {
  int id = blockIdx.x * 256 + threadIdx.x;
  if (id >= 24576) return;
  int c = id % 3;
  trans1[id] = lrelu(fmaf(xt1[id], sc[c], sc[3 + c]));
}

// ---------------- x2 = edgefeat(IF,134) @ w2(16x134)^T, store + stats ----------------
__global__ __launch_bounds__(256) void x2_kernel(const float* __restrict__ IF, const int* __restrict__ idx,
                                                 const float* __restrict__ W, float* __restrict__ x2,
                                                 double* __restrict__ acc) {
  __shared__ float WT[134 * 16];
  __shared__ double dred[256];
  int tid = threadIdx.x;
  for (int i = tid; i < 134 * 16; i += 256) { int c = i & 15, j = i >> 4; WT[j * 16 + c] = W[c * 134 + j]; }
  __syncthreads();
  int c = tid & 15;
  double ls = 0, lq = 0;
  const int total = 245760 * 16;
  int stride = gridDim.x << 8;
  for (int id = (blockIdx.x << 8) + tid; id < total; id += stride) {
    int p = id >> 4;
    int bn = p / 30; int b = bn >> 11;
    int nb = idx[p];
    const float* cen = IF + (size_t)bn * 67;
    const float* nbp = IF + (size_t)((b << 11) + nb) * 67;
    float a = 0.f;
    for (int j = 0; j < 67; ++j) {
      float cj = cen[j];
      a += cj * WT[j * 16 + c];
      a += (nbp[j] - cj) * WT[(67 + j) * 16 + c];
    }
    x2[id] = a;
    ls += a; lq += (double)a * a;
  }
  dred[tid] = ls; __syncthreads();
  if (tid < 16) { double v = 0; for (int i = tid; i < 256; i += 16) v += dred[i]; atomicAdd(&acc[tid], v); }
  __syncthreads();
  dred[tid] = lq; __syncthreads();
  if (tid < 16) { double v = 0; for (int i = tid; i < 256; i += 16) v += dred[i]; atomicAdd(&acc[16 + tid], v); }
}

// ---------------- out4=bnlrelu(x2); nm2/ne2 over K; x3 = [nm2,ne2] @ w3^T ----------------
__global__ __launch_bounds__(256) void k5_kernel(const float* __restrict__ x2, const float* __restrict__ sc2,
                                                 const float* __restrict__ W3, float* __restrict__ nm2,
                                                 float* __restrict__ ne2, float* __restrict__ x3) {
  __shared__ float W3T[32 * 16];
  __shared__ float o5[4][32];
  int tid = threadIdx.x;
  for (int i = tid; i < 512; i += 256) { int c = i & 15, j = i >> 4; W3T[j * 16 + c] = W3[c * 32 + j]; }
  __syncthreads();
  int lane = tid & 63, w = tid >> 6;
  int bn = blockIdx.x * 4 + w;
  int c = lane & 15, kq = lane >> 4;
  float s = sc2[c], t = sc2[16 + c];
  float lm = -3.4e38f, lsm = 0.f;
  const float* xp = x2 + (size_t)bn * 30 * 16;
  for (int k = kq; k < 30; k += 4) {
    float v = lrelu(fmaf(xp[k * 16 + c], s, t));
    lm = fmaxf(lm, v); lsm += v;
  }
  float lm2 = fmaxf(lm, __shfl_down(lm, 32, 64)); lm2 = fmaxf(lm2, __shfl_down(lm2, 16, 64));
  float ls2 = lsm + __shfl_down(lsm, 32, 64); ls2 = ls2 + __shfl_down(ls2, 16, 64);
  if (lane < 16) {
    float mean = ls2 / 30.f;
    nm2[bn * 16 + c] = lm2;
    ne2[bn * 16 + c] = mean;
    o5[w][c] = lm2; o5[w][16 + c] = mean;
  }
  __syncthreads();
  if (lane < 16) {
    float a = 0.f;
#pragma unroll
    for (int j = 0; j < 32; ++j) a += o5[w][j] * W3T[j * 16 + c];
    x3[bn * 16 + c] = a;
  }
}

// ---------------- final pack (4 identical graph copies) ----------------
__global__ void out_kernel(const float* __restrict__ x3, const float* __restrict__ sc3,
                           const float* __restrict__ nm2, const float* __restrict__ ne2,
                           float* __restrict__ out) {
  int id = blockIdx.x * 256 + threadIdx.x;
  if (id >= 4 * 16 * 2048) return;
  int n = id & 2047;
  int j = (id >> 11) & 15;
  int b = id >> 15;
  int bn = (b << 11) + n;
  float v5 = lrelu(fmaf(x3[bn * 16 + j], sc3[j], sc3[16 + j]));
  float vm = nm2[bn * 16 + j];
  float ve = ne2[bn * 16 + j];
#pragma unroll
  for (int g = 0; g < 4; ++g) {
    size_t base = (size_t)(b * 64 + g * 16 + j) * 2048 + n;
    out[base] = v5;
    out[524288 + base] = vm;
    out[1048576 + base] = ve;
  }
}

extern "C" void kernel_launch(void* const* d_in, const int* in_sizes, int n_in,
                              void* d_out, int out_size, void* d_ws, size_t ws_size,
                              hipStream_t stream) {
  (void)n_in; (void)out_size; (void)ws_size;
  const float* input_image = (const float*)d_in[0];
  bool dict = (in_sizes[10] == 384);
  int I_wo1, I_go1, I_bo1, I_wo2, I_go2, I_bo2, I_wo3, I_go3, I_bo3;
  int I_w1, I_g1, I_b1, I_w2, I_g2, I_b2, I_w3, I_g3, I_b3;
  int I_fc1w, I_fc1b, I_fc2w, I_fc2b, I_tw, I_tb;
  if (dict) {
    I_wo1 = 10; I_go1 = 11; I_bo1 = 12; I_wo2 = 13; I_go2 = 14; I_bo2 = 15;
    I_wo3 = 16; I_go3 = 17; I_bo3 = 18;
    I_w1 = 19; I_g1 = 20; I_b1 = 21; I_w2 = 22; I_g2 = 23; I_b2 = 24; I_w3 = 25; I_g3 = 26; I_b3 = 27;
    I_fc1w = 28; I_fc1b = 29; I_fc2w = 30; I_fc2b = 31; I_tw = 32; I_tb = 33;
  } else {
    I_fc1w = 10; I_fc1b = 11; I_fc2w = 12; I_fc2b = 13; I_tw = 14; I_tb = 15;
    I_wo1 = 16; I_go1 = 17; I_bo1 = 18; I_wo2 = 19; I_go2 = 20; I_bo2 = 21;
    I_wo3 = 22; I_go3 = 23; I_bo3 = 24;
    I_w1 = 25; I_g1 = 26; I_b1 = 27; I_w2 = 28; I_g2 = 29; I_b2 = 30; I_w3 = 31; I_g3 = 32; I_b3 = 33;
  }
#define FIN(i) ((const float*)d_in[i])
  float* ws = (float*)d_ws;
  float* pc      = ws;
  float* pct     = ws + 24576;
  float* trans1  = ws + 49152;
  int*   idx1    = (int*)(ws + 73728);
  int*   idx2    = (int*)(ws + 319488);
  int*   idx3    = (int*)(ws + 565248);
  float* m128b   = ws + 811008;                 // 8192*128
  float* catb    = ws + 1859584;                // 8192*128
  unsigned* maxmapb = (unsigned*)(ws + 2908160);// 4096
  unsigned* minmapb = (unsigned*)(ws + 2912256);// 4096
  float* m128mx  = ws + 2916352;                // 8192*128 pre-BN max
  float* m128mn  = ws + 3964928;                // 8192*128 pre-BN min
  float* gmaxb   = ws + 10248192;
  float* transf  = ws + 10252288;
  float* xo3T    = ws + 10252352;               // 64 x 8192
  float* IFb     = ws + 10776640;
  float* xt1b    = ws + 11325504;
  float* x2b     = ws + 11350080;
  float* nm2b    = ws + 15282240;
  float* ne2b    = ws + 15413312;
  float* x3b     = ws + 15544384;
  double* acc    = (double*)(ws + 15675456);    // 4096 doubles
  float* sc      = ws + 15683648;               // 4096 floats
  const double CNT_E = 245760.0, CNT_P = 8192.0;
  const int A64 = 0, A128 = 128, A1024 = 384, AO1 = 2432, AO2 = 2560, AO3 = 2688, AT1 = 2816, A2 = 2822, A3 = 2854;

  zero_kernel<<<32, 256, 0, stream>>>((float*)acc, 8192);
  iminit_kernel<<<16, 256, 0, stream>>>(maxmapb, minmapb);
  pc_kernel<<<96, 256, 0, stream>>>(input_image, pc);
  knn_kernel<<<2048, 256, 0, stream>>>(pc, idx1);
  mom6_kernel<<<32, 256, 0, stream>>>(pc, idx1, acc + A64);
  finE1_kernel<<<1, 64, 0, stream>>>(acc + A64, FIN(1), FIN(2), FIN(3), sc + A64);
  edgeA_kernel<<<4096, 64, 0, stream>>>(pc, idx1, FIN(1), sc + A64, FIN(4), m128mx, m128mn, acc + A128);
  fin_kernel<<<1, 256, 0, stream>>>(acc + A128, FIN(5), FIN(6), CNT_E, 128, sc + A128);
  applyA_kernel<<<4096, 256, 0, stream>>>(m128mx, m128mn, sc + A128, m128b);
  cmm1024_kernel<<<1024, 256, 0, stream>>>(m128b, FIN(7), acc + A1024, maxmapb, minmapb);
  fin1024_kernel<<<4, 256, 0, stream>>>(acc + A1024, FIN(8), FIN(9), maxmapb, minmapb, gmaxb);
  fc_kernel<<<4, 256, 0, stream>>>(gmaxb, FIN(I_fc1w), FIN(I_fc1b), FIN(I_fc2w), FIN(I_fc2b), FIN(I_tw), FIN(I_tb), transf);
  pct_kernel<<<32, 256, 0, stream>>>(pc, transf, pct);
  knn_kernel<<<2048, 256, 0, stream>>>(pct, idx2);
  mom6_kernel<<<32, 256, 0, stream>>>(pct, idx2, acc + AO1);
  finE1_kernel<<<1, 64, 0, stream>>>(acc + AO1, FIN(I_wo1), FIN(I_go1), FIN(I_bo1), sc + AO1);
  statsB_kernel<<<4096, 64, 0, stream>>>(pct, idx2, FIN(I_wo1), sc + AO1, FIN(I_wo2), acc + AO2);
  fin_kernel<<<1, 256, 0, stream>>>(acc + AO2, FIN(I_go2), FIN(I_bo2), CNT_E, 64, sc + AO2);
  poolB_kernel<<<4096, 64, 0, stream>>>(pct, idx2, FIN(I_wo1), sc + AO1, FIN(I_wo2), sc + AO2, catb);
  xo3g_kernel<<<128, 256, 0, stream>>>(catb, FIN(I_wo3), xo3T);
  rstats_kernel<<<64, 256, 0, stream>>>(xo3T, 8192, 64, acc + AO3);
  fin_kernel<<<1, 256, 0, stream>>>(acc + AO3, FIN(I_go3), FIN(I_bo3), CNT_P, 64, sc + AO3);
  if_kernel<<<2144, 256, 0, stream>>>(pct, xo3T, sc + AO3, IFb);
  xt1_kernel<<<96, 256, 0, stream>>>(IFb, FIN(I_w1), xt1b);
  stats3_kernel<<<32, 256, 0, stream>>>(xt1b, 24576, acc + AT1);
  fin_kernel<<<1, 256, 0, stream>>>(acc + AT1, FIN(I_g1), FIN(I_b1), CNT_P, 3, sc + AT1);
  t1_kernel<<<96, 256, 0, stream>>>(xt1b, sc + AT1, trans1);
  knn_kernel<<<2048, 256, 0, stream>>>(trans1, idx3);
  x2_kernel<<<512, 256, 0, stream>>>(IFb, idx3, FIN(I_w2), x2b, acc + A2);
  fin_kernel<<<1, 256, 0, stream>>>(acc + A2, FIN(I_g2), FIN(I_b2), CNT_E, 16, sc + A2);
  k5_kernel<<<2048, 256, 0, stream>>>(x2b, sc + A2, FIN(I_w3), nm2b, ne2b, x3b);
  dstats_kernel<<<256, 256, 0, stream>>>(x3b, 131072, 16, acc + A3);
  fin_kernel<<<1, 256, 0, stream>>>(acc + A3, FIN(I_g3), FIN(I_b3), CNT_P, 16, sc + A3);
  out_kernel<<<512, 256, 0, stream>>>(x3b, sc + A3, nm2b, ne2b, (float*)d_out);
#undef FIN
}

// Round 13
// 1249.738 us; speedup vs baseline: 1.8117x; 1.0098x over previous
//
#include <hip/hip_runtime.h>

// offset_deform: DGCNN-style forward. B=4, N=2048, K=30.
// NUM_GRAPH loop is iteration-invariant -> compute once, pack 4x.
// R13: revert to R10 (best verified: 1183us, 256-thr XOR-swizzle kernels;
//      single-wave experiment R11/R12 empirically worse) + ONE tweak:
//      #pragma unroll 2 on the 32-channel q-loops of edgeA/statsB/poolB so
//      channel q+1's s_load overlaps channel q's 64 FMAs. Per-channel
//      accumulation order unchanged -> bit-identical numerics.

#define DEV __device__ __forceinline__
DEV float lrelu(float y) { return y > 0.f ? y : 0.2f * y; }
// monotone float->unsigned map (order-preserving for all finite floats)
DEV unsigned fmap(float x) {
  unsigned u = __float_as_uint(x);
  return (u & 0x80000000u) ? ~u : (u | 0x80000000u);
}
DEV float funmap(unsigned m) {
  unsigned u = (m & 0x80000000u) ? (m & 0x7FFFFFFFu) : ~m;
  return __uint_as_float(u);
}

// ---------------- utility ----------------
__global__ void zero_kernel(float* p, int n) {
  int id = blockIdx.x * 256 + threadIdx.x;
  if (id < n) p[id] = 0.f;
}

__global__ void iminit_kernel(unsigned* maxm, unsigned* minm) {
  int id = blockIdx.x * 256 + threadIdx.x;
  if (id < 4096) { maxm[id] = 0u; minm[id] = 0xFFFFFFFFu; }
}

// input (B,3,N) -> pc (B,N,3)
__global__ void pc_kernel(const float* __restrict__ in, float* __restrict__ pc) {
  int id = blockIdx.x * 256 + threadIdx.x;
  if (id >= 4 * 3 * 2048) return;
  int n = id & 2047;
  int c = (id >> 11) % 3;
  int b = id / (3 * 2048);
  pc[((b << 11) + n) * 3 + c] = in[id];
}

// ---------------- knn: wave per query point, per-lane top-4 list ----------------
// (byte-identical to R6/R9/R10 -- known-good, absmax 0.1015625)
__global__ __launch_bounds__(256) void knn_kernel(const float* __restrict__ pts, int* __restrict__ idx_out) {
  int tid = threadIdx.x;
  int w = tid >> 6, lane = tid & 63;
  int bn = (blockIdx.x << 2) + w;
  int b = bn >> 11;
  const float* base = pts + (b << 11) * 3;
  double qx = pts[bn * 3 + 0], qy = pts[bn * 3 + 1], qz = pts[bn * 3 + 2];
  double sqn = qx * qx + qy * qy + qz * qz;
  double d[32];
#pragma unroll
  for (int i = 0; i < 32; ++i) {
    int m = lane + (i << 6);
    double px = base[m * 3 + 0], py = base[m * 3 + 1], pz = base[m * 3 + 2];
    double v = sqn - 2.0 * (qx * px + qy * py + qz * pz) + (px * px + py * py + pz * pz);
    d[i] = v;
  }
  unsigned used = 0u;
  double l0, l1, l2, l3; int p0, p1, p2, p3;
#define KNN_PASS(LV, PV)                                              \
  {                                                                   \
    double cm = 1e300; int cp = 0x7fffffff; int ci = 0;               \
    _Pragma("unroll")                                                 \
    for (int i = 0; i < 32; ++i) {                                    \
      double v = ((used >> i) & 1u) ? 1e300 : d[i];                   \
      if (v < cm) { cm = v; cp = lane + (i << 6); ci = i; }           \
    }                                                                 \
    used |= 1u << ci; LV = cm; PV = cp;                               \
  }
  KNN_PASS(l0, p0)
  KNN_PASS(l1, p1)
  KNN_PASS(l2, p2)
  KNN_PASS(l3, p3)
  int cnt = 4;
  int* out = idx_out + bn * 30;
  for (int it = 0; it < 30; ++it) {
    double gv = l0; int gp = p0;
#pragma unroll
    for (int off = 1; off < 64; off <<= 1) {
      double ov = __shfl_xor(gv, off, 64);
      int op = __shfl_xor(gp, off, 64);
      if (ov < gv || (ov == gv && op < gp)) { gv = ov; gp = op; }
    }
    if (lane == 0) out[it] = gp;
    if (lane == (gp & 63)) {          // owner: pop head
      l0 = l1; p0 = p1; l1 = l2; p1 = p2; l2 = l3; p2 = p3;
      l3 = 1e300; p3 = 0x7fffffff;
      cnt--;
      if (cnt == 0) {                 // rare: refill with true next-best
        KNN_PASS(l0, p0)
        cnt = 1;
      }
    }
  }
#undef KNN_PASS
}

// ---------------- mom6: S[6] + upper-tri M[21] of edge features ----------------
__global__ __launch_bounds__(256) void mom6_kernel(const float* __restrict__ pts, const int* __restrict__ idx,
                                                   double* __restrict__ acc) {
  __shared__ double sred[4][27];
  int tid = threadIdx.x;
  int lane = tid & 63, w = tid >> 6;
  double m[27];
#pragma unroll
  for (int i = 0; i < 27; ++i) m[i] = 0.0;
  int stride = gridDim.x << 8;
  for (int e = (blockIdx.x << 8) + tid; e < 245760; e += stride) {
    int bn = e / 30; int b = bn >> 11;
    int nb = idx[e];
    const float* cen = pts + bn * 3;
    const float* nbp = pts + ((b << 11) + nb) * 3;
    float f[6];
    f[0] = cen[0]; f[1] = cen[1]; f[2] = cen[2];
    f[3] = nbp[0] - f[0]; f[4] = nbp[1] - f[1]; f[5] = nbp[2] - f[2];
    int t = 6;
#pragma unroll
    for (int i = 0; i < 6; ++i) {
      m[i] += f[i];
#pragma unroll
      for (int j = i; j < 6; ++j) m[t++] += (double)f[i] * f[j];
    }
  }
#pragma unroll
  for (int i = 0; i < 27; ++i) {
    double v = m[i];
    v += __shfl_xor(v, 1, 64); v += __shfl_xor(v, 2, 64); v += __shfl_xor(v, 4, 64);
    v += __shfl_xor(v, 8, 64); v += __shfl_xor(v, 16, 64); v += __shfl_xor(v, 32, 64);
    m[i] = v;
  }
  if (lane == 0) {
#pragma unroll
    for (int i = 0; i < 27; ++i) sred[w][i] = m[i];
  }
  __syncthreads();
  if (tid < 27) atomicAdd(&acc[tid], sred[0][tid] + sred[1][tid] + sred[2][tid] + sred[3][tid]);
}

// finE1: per-channel mean/var from moment form  mean=w.S/E, E[x^2]=w^T M w / E
__global__ void finE1_kernel(const double* __restrict__ acc, const float* __restrict__ W,
                             const float* __restrict__ g, const float* __restrict__ bb,
                             float* __restrict__ sc) {
  int c = threadIdx.x;
  if (c >= 64) return;
  double wv[6];
#pragma unroll
  for (int i = 0; i < 6; ++i) wv[i] = W[c * 6 + i];
  double s = 0.0;
#pragma unroll
  for (int i = 0; i < 6; ++i) s += wv[i] * acc[i];
  double q = 0.0; int t = 6;
#pragma unroll
  for (int i = 0; i < 6; ++i)
#pragma unroll
    for (int j = i; j < 6; ++j) {
      double mm = acc[t++];
      q += (i == j) ? wv[i] * wv[i] * mm : 2.0 * wv[i] * wv[j] * mm;
    }
  const double E = 245760.0;
  double mean = s / E;
  double var = q / E - mean * mean;
  if (var < 0) var = 0;
  float sf = g[c] * (float)(1.0 / sqrt(var + 1e-5));
  sc[c] = sf;
  sc[64 + c] = bb[c] - (float)mean * sf;
}

// ---------------- edgeA: fused stats + pre-BN max/min pool (LDS XOR-swizzle) ----------------
// wave = 2 points, lane&31 = k. Phase1 (per chunk of 32 ch): lane writes its
// edge's channel-q value to slot k^q. Phase2: lane = (pt, ch) reads slot
// kk^ch. 40960 B LDS -> 3-4 blocks/CU. q-loop unroll 2: overlap next
// channel's s_load with current channel's FMAs. Grid MUST be 1024.
__global__ __launch_bounds__(256) void edgeA_kernel(const float* __restrict__ pts, const int* __restrict__ idx,
                                                    const float* __restrict__ W1, const float* __restrict__ sc1,
                                                    const float* __restrict__ W2,
                                                    float* __restrict__ mxout, float* __restrict__ mnout,
                                                    double* __restrict__ acc) {
  __shared__ float vbuf[4][2][32][32];
  __shared__ double sred[4][32][8];
  int tid = threadIdx.x;
  int lane = tid & 63;
  int wv = tid >> 6;
  int k = lane & 31;
  int pt = lane >> 5;
  int bn = (blockIdx.x << 3) + (wv << 1) + pt;
  int b = bn >> 11;
  bool valid = k < 30;
  int nb = idx[bn * 30 + (valid ? k : 0)];
  const float* cen = pts + bn * 3;
  const float* nbp = pts + ((b << 11) + nb) * 3;
  float cx = cen[0], cy = cen[1], cz = cen[2];
  float dx = nbp[0] - cx, dy = nbp[1] - cy, dz = nbp[2] - cz;
  float y[64];
#pragma unroll
  for (int j = 0; j < 64; ++j) {
    float x = cx * W1[j * 6 + 0] + cy * W1[j * 6 + 1] + cz * W1[j * 6 + 2]
            + dx * W1[j * 6 + 3] + dy * W1[j * 6 + 4] + dz * W1[j * 6 + 5];
    y[j] = lrelu(fmaf(x, sc1[j], sc1[64 + j]));
  }
  int ch = lane & 31, pt2 = lane >> 5;
  int bn2 = (blockIdx.x << 3) + (wv << 1) + pt2;
  double aS[4] = {0, 0, 0, 0}, aQ[4] = {0, 0, 0, 0};
#pragma unroll
  for (int cc = 0; cc < 4; ++cc) {
#pragma unroll 2
    for (int q = 0; q < 32; ++q) {
      int c = cc * 32 + q;
      const float* w = W2 + c * 64;
      float a0 = 0.f, a1 = 0.f, a2 = 0.f, a3 = 0.f;
#pragma unroll
      for (int j = 0; j < 64; j += 4) {
        a0 = fmaf(y[j], w[j], a0); a1 = fmaf(y[j + 1], w[j + 1], a1);
        a2 = fmaf(y[j + 2], w[j + 2], a2); a3 = fmaf(y[j + 3], w[j + 3], a3);
      }
      vbuf[wv][pt][q][k ^ q] = (a0 + a1) + (a2 + a3);
    }
    __syncthreads();
    const float* vr = &vbuf[wv][pt2][ch][0];
    float v0 = vr[0 ^ ch];
    float mx = v0, mn = v0, sm = v0, qq = v0 * v0;
#pragma unroll
    for (int kkk = 1; kkk < 30; ++kkk) {
      float v = vr[kkk ^ ch];
      mx = fmaxf(mx, v); mn = fminf(mn, v);
      sm += v; qq = fmaf(v, v, qq);
    }
    mxout[bn2 * 128 + cc * 32 + ch] = mx;
    mnout[bn2 * 128 + cc * 32 + ch] = mn;
    float sm1 = __shfl_xor(sm, 32, 64);
    float qq1 = __shfl_xor(qq, 32, 64);
    if (lane < 32) { aS[cc] += (double)(sm + sm1); aQ[cc] += (double)(qq + qq1); }
    __syncthreads();
  }
  if (lane < 32) {
#pragma unroll
    for (int cc = 0; cc < 4; ++cc) { sred[wv][lane][cc * 2] = aS[cc]; sred[wv][lane][cc * 2 + 1] = aQ[cc]; }
  }
  __syncthreads();
  {
    int l = tid >> 3, j = tid & 7;
    double t = sred[0][l][j] + sred[1][l][j] + sred[2][l][j] + sred[3][l][j];
    int c = (j >> 1) * 32 + l;
    atomicAdd(&acc[(j & 1) * 128 + c], t);
  }
}

// applyA: m128[bn][c] = lrelu(s * (s>=0 ? mx : mn) + t)
__global__ void applyA_kernel(const float* __restrict__ mx, const float* __restrict__ mn,
                              const float* __restrict__ sc, float* __restrict__ m128) {
  int id = blockIdx.x * 256 + threadIdx.x;
  if (id >= 8192 * 128) return;
  int c = id & 127;
  float s = sc[c], t = sc[128 + c];
  float sel = (s >= 0.f) ? mx[id] : mn[id];
  m128[id] = lrelu(fmaf(sel, s, t));
}

// ---------------- statsB: sum/sumsq of x2 = bnlrelu(y) @ W2(64x64)^T (LDS XOR-swizzle) ----------------
// Grid MUST be 1024. 36864 B LDS.
__global__ __launch_bounds__(256) void statsB_kernel(const float* __restrict__ pts, const int* __restrict__ idx,
                                                     const float* __restrict__ W1, const float* __restrict__ sc1,
                                                     const float* __restrict__ W2, double* __restrict__ acc) {
  __shared__ float vbuf[4][2][32][32];
  __shared__ double sred[4][32][4];
  int tid = threadIdx.x;
  int lane = tid & 63;
  int wv = tid >> 6;
  int k = lane & 31;
  int pt = lane >> 5;
  int bn = (blockIdx.x << 3) + (wv << 1) + pt;
  int b = bn >> 11;
  bool valid = k < 30;
  int nb = idx[bn * 30 + (valid ? k : 0)];
  const float* cen = pts + bn * 3;
  const float* nbp = pts + ((b << 11) + nb) * 3;
  float cx = cen[0], cy = cen[1], cz = cen[2];
  float dx = nbp[0] - cx, dy = nbp[1] - cy, dz = nbp[2] - cz;
  float y[64];
#pragma unroll
  for (int j = 0; j < 64; ++j) {
    float x = cx * W1[j * 6 + 0] + cy * W1[j * 6 + 1] + cz * W1[j * 6 + 2]
            + dx * W1[j * 6 + 3] + dy * W1[j * 6 + 4] + dz * W1[j * 6 + 5];
    y[j] = lrelu(fmaf(x, sc1[j], sc1[64 + j]));
  }
  int ch = lane & 31, pt2 = lane >> 5;
  double aS[2] = {0, 0}, aQ[2] = {0, 0};
#pragma unroll
  for (int cc = 0; cc < 2; ++cc) {
#pragma unroll 2
    for (int q = 0; q < 32; ++q) {
      int c = cc * 32 + q;
      const float* w = W2 + c * 64;
      float a0 = 0.f, a1 = 0.f, a2 = 0.f, a3 = 0.f;
#pragma unroll
      for (int j = 0; j < 64; j += 4) {
        a0 = fmaf(y[j], w[j], a0); a1 = fmaf(y[j + 1], w[j + 1], a1);
        a2 = fmaf(y[j + 2], w[j + 2], a2); a3 = fmaf(y[j + 3], w[j + 3], a3);
      }
      vbuf[wv][pt][q][k ^ q] = (a0 + a1) + (a2 + a3);
    }
    __syncthreads();
    const float* vr = &vbuf[wv][pt2][ch][0];
    float v0 = vr[0 ^ ch];
    float sm = v0, qq = v0 * v0;
#pragma unroll
    for (int kkk = 1; kkk < 30; ++kkk) {
      float v = vr[kkk ^ ch];
      sm += v; qq = fmaf(v, v, qq);
    }
    float sm1 = __shfl_xor(sm, 32, 64);
    float qq1 = __shfl_xor(qq, 32, 64);
    if (lane < 32) { aS[cc] += (double)(sm + sm1); aQ[cc] += (double)(qq + qq1); }
    __syncthreads();
  }
  if (lane < 32) {
#pragma unroll
    for (int cc = 0; cc < 2; ++cc) { sred[wv][lane][cc * 2] = aS[cc]; sred[wv][lane][cc * 2 + 1] = aQ[cc]; }
  }
  __syncthreads();
  if (tid < 128) {
    int l = tid >> 2, j = tid & 3;
    double t = sred[0][l][j] + sred[1][l][j] + sred[2][l][j] + sred[3][l][j];
    int c = (j >> 1) * 32 + l;
    atomicAdd(&acc[(j & 1) * 64 + c], t);
  }
}

// ---------------- poolB: cat = [max_k v, mean_k v], v = bnlrelu(x2) (LDS XOR-swizzle) ----------------
// Grid MUST be 1024. 32768 B LDS.
__global__ __launch_bounds__(256) void poolB_kernel(const float* __restrict__ pts, const int* __restrict__ idx,
                                                    const float* __restrict__ W1, const float* __restrict__ sc1,
                                                    const float* __restrict__ W2, const float* __restrict__ sc2,
                                                    float* __restrict__ cat) {
  __shared__ float vbuf[4][2][32][32];
  int tid = threadIdx.x;
  int lane = tid & 63;
  int wv = tid >> 6;
  int k = lane & 31;
  int pt = lane >> 5;
  int bn = (blockIdx.x << 3) + (wv << 1) + pt;
  int b = bn >> 11;
  bool valid = k < 30;
  int nb = idx[bn * 30 + (valid ? k : 0)];
  const float* cen = pts + bn * 3;
  const float* nbp = pts + ((b << 11) + nb) * 3;
  float cx = cen[0], cy = cen[1], cz = cen[2];
  float dx = nbp[0] - cx, dy = nbp[1] - cy, dz = nbp[2] - cz;
  float y[64];
#pragma unroll
  for (int j = 0; j < 64; ++j) {
    float x = cx * W1[j * 6 + 0] + cy * W1[j * 6 + 1] + cz * W1[j * 6 + 2]
            + dx * W1[j * 6 + 3] + dy * W1[j * 6 + 4] + dz * W1[j * 6 + 5];
    y[j] = lrelu(fmaf(x, sc1[j], sc1[64 + j]));
  }
  int ch = lane & 31, pt2 = lane >> 5;
  int bn2 = (blockIdx.x << 3) + (wv << 1) + pt2;
#pragma unroll
  for (int cc = 0; cc < 2; ++cc) {
#pragma unroll 2
    for (int q = 0; q < 32; ++q) {
      int c = cc * 32 + q;
      const float* w = W2 + c * 64;
      float a0 = 0.f, a1 = 0.f, a2 = 0.f, a3 = 0.f;
#pragma unroll
      for (int j = 0; j < 64; j += 4) {
        a0 = fmaf(y[j], w[j], a0); a1 = fmaf(y[j + 1], w[j + 1], a1);
        a2 = fmaf(y[j + 2], w[j + 2], a2); a3 = fmaf(y[j + 3], w[j + 3], a3);
      }
      vbuf[wv][pt][q][k ^ q] = (a0 + a1) + (a2 + a3);
    }
    __syncthreads();
    int c2 = cc * 32 + ch;
    float s = sc2[c2], t = sc2[64 + c2];
    const float* vr = &vbuf[wv][pt2][ch][0];
    float v0 = lrelu(fmaf(vr[0 ^ ch], s, t));
    float mx = v0, sm = v0;
#pragma unroll
    for (int kkk = 1; kkk < 30; ++kkk) {
      float v = lrelu(fmaf(vr[kkk ^ ch], s, t));
      mx = fmaxf(mx, v); sm += v;
    }
    cat[bn2 * 128 + cc * 32 + ch] = mx;
    cat[bn2 * 128 + 64 + cc * 32 + ch] = sm * (1.f / 30.f);
    __syncthreads();
  }
}

// ---------------- xo3T[c][bn] = cat[bn][:] @ wo3[c][:] ----------------
__global__ __launch_bounds__(256) void xo3g_kernel(const float* __restrict__ cat, const float* __restrict__ W3,
                                                   float* __restrict__ xo3T) {
  int tid = threadIdx.x;
  int lane = tid & 63, cw = tid >> 6;
  int bn = (blockIdx.x << 6) + lane;
  const float* cr = cat + bn * 128;
  float a[16];
#pragma unroll
  for (int q = 0; q < 16; ++q) a[q] = 0.f;
  for (int j = 0; j < 128; ++j) {
    float v = cr[j];
#pragma unroll
    for (int q = 0; q < 16; ++q) a[q] += v * W3[(cw * 16 + q) * 128 + j];
  }
#pragma unroll
  for (int q = 0; q < 16; ++q) xo3T[(cw * 16 + q) * 8192 + bn] = a[q];
}

// ---------------- row stats: x is [C][E], one block per row ----------------
__global__ __launch_bounds__(256) void rstats_kernel(const float* __restrict__ x, int E, int C,
                                                     double* __restrict__ acc) {
  __shared__ double rd[256];
  int c = blockIdx.x, tid = threadIdx.x;
  const float* r = x + (size_t)c * E;
  double ls = 0, lq = 0;
  for (int i = tid; i < E; i += 256) { float v = r[i]; ls += v; lq += (double)v * v; }
  rd[tid] = ls; __syncthreads();
  for (int s = 128; s > 0; s >>= 1) { if (tid < s) rd[tid] += rd[tid + s]; __syncthreads(); }
  if (tid == 0) acc[c] = rd[0];
  __syncthreads();
  rd[tid] = lq; __syncthreads();
  for (int s = 128; s > 0; s >>= 1) { if (tid < s) rd[tid] += rd[tid + s]; __syncthreads(); }
  if (tid == 0) acc[C + c] = rd[0];
}

// ---------------- cmm1024: x=m128@W^T fused with {sum,sumsq,max,min} ----------------
__global__ __launch_bounds__(256) void cmm1024_kernel(const float* __restrict__ m128, const float* __restrict__ W,
                                                      double* __restrict__ acc, unsigned* __restrict__ maxm,
                                                      unsigned* __restrict__ minm) {
  __shared__ float mt[64 * 132];
  int tid = threadIdx.x;
  int lane = tid & 63;
  int b = blockIdx.x >> 8;
  int cg = (blockIdx.x >> 2) & 63;
  int ns = blockIdx.x & 3;
  int wu = __builtin_amdgcn_readfirstlane(tid >> 6);
  int cbase = cg * 16 + wu * 4;
  const float* wr = W + (size_t)cbase * 128;
  double ls[4] = {0, 0, 0, 0}, lq[4] = {0, 0, 0, 0};
  float mx[4], mn[4];
#pragma unroll
  for (int q = 0; q < 4; ++q) { mx[q] = -3.4e38f; mn[q] = 3.4e38f; }
  for (int ch = 0; ch < 8; ++ch) {
    int n0 = (ns << 9) + (ch << 6);
    __syncthreads();
    for (int i = tid; i < 2048; i += 256) {
      int r = i >> 5, jj = (i & 31) << 2;
      *(float4*)&mt[r * 132 + jj] = *(const float4*)&m128[(size_t)((b << 11) + n0 + r) * 128 + jj];
    }
    __syncthreads();
    float a[4] = {0.f, 0.f, 0.f, 0.f};
    const float* mrow = &mt[lane * 132];
#pragma unroll
    for (int j = 0; j < 128; j += 4) {
      float4 mv = *(const float4*)&mrow[j];
#pragma unroll
      for (int q = 0; q < 4; ++q) {
        const float* wq = wr + q * 128 + j;
        a[q] = fmaf(mv.x, wq[0], a[q]);
        a[q] = fmaf(mv.y, wq[1], a[q]);
        a[q] = fmaf(mv.z, wq[2], a[q]);
        a[q] = fmaf(mv.w, wq[3], a[q]);
      }
    }
#pragma unroll
    for (int q = 0; q < 4; ++q) {
      ls[q] += a[q]; lq[q] += (double)a[q] * a[q];
      mx[q] = fmaxf(mx[q], a[q]); mn[q] = fminf(mn[q], a[q]);
    }
  }
#pragma unroll
  for (int q = 0; q < 4; ++q) {
    double s = ls[q], sq = lq[q];
    float xm = mx[q], xn = mn[q];
    for (int off = 1; off < 64; off <<= 1) {
      s += __shfl_xor(s, off, 64);
      sq += __shfl_xor(sq, off, 64);
      xm = fmaxf(xm, __shfl_xor(xm, off, 64));
      xn = fminf(xn, __shfl_xor(xn, off, 64));
    }
    if (lane == 0) {
      int c = cbase + q;
      atomicAdd(&acc[c], s);
      atomicAdd(&acc[1024 + c], sq);
      atomicMax(&maxm[(b << 10) + c], fmap(xm));
      atomicMin(&minm[(b << 10) + c], fmap(xn));
    }
  }
}

// fin1024: stats -> (s,t); gmax = lrelu(s*extreme + t), extreme by sign(s)
__global__ void fin1024_kernel(const double* __restrict__ acc, const float* __restrict__ g,
                               const float* __restrict__ bb, const unsigned* __restrict__ maxm,
                               const unsigned* __restrict__ minm, float* __restrict__ gmax) {
  int c = blockIdx.x * 256 + threadIdx.x;
  if (c >= 1024) return;
  double mean = acc[c] / 8192.0;
  double var = acc[1024 + c] / 8192.0 - mean * mean;
  if (var < 0) var = 0;
  float s = g[c] * (float)(1.0 / sqrt(var + 1e-5));
  float t = bb[c] - (float)mean * s;
  for (int b = 0; b < 4; ++b) {
    float xm = (s >= 0.f) ? funmap(maxm[(b << 10) + c]) : funmap(minm[(b << 10) + c]);
    gmax[(b << 10) + c] = lrelu(fmaf(xm, s, t));
  }
}

// ---------------- fc1 -> fc2 -> transform (B,9) ----------------
__global__ __launch_bounds__(256) void fc_kernel(const float* __restrict__ gmax,
                                                 const float* __restrict__ fc1w, const float* __restrict__ fc1b,
                                                 const float* __restrict__ fc2w, const float* __restrict__ fc2b,
                                                 const float* __restrict__ tw, const float* __restrict__ tb,
                                                 float* __restrict__ transform) {
  __shared__ float net[1024];
  __shared__ float h1[512];
  __shared__ float h2[256];
  int b = blockIdx.x, tid = threadIdx.x;
  for (int i = tid; i < 1024; i += 256) net[i] = gmax[b * 1024 + i];
  __syncthreads();
  for (int o = tid; o < 512; o += 256) {
    float a = fc1b[o];
    const float* w = fc1w + o * 1024;
    for (int j = 0; j < 1024; ++j) a += net[j] * w[j];
    h1[o] = a;
  }
  __syncthreads();
  {
    int o = tid;
    float a = fc2b[o];
    const float* w = fc2w + o * 512;
    for (int j = 0; j < 512; ++j) a += h1[j] * w[j];
    h2[o] = a;
  }
  __syncthreads();
  if (tid < 9) {
    float a = 0.f;
    for (int i = 0; i < 256; ++i) a += h2[i] * tw[i * 9 + tid];
    float eye = (tid == 0 || tid == 4 || tid == 8) ? 1.f : 0.f;
    transform[b * 9 + tid] = a + eye + tb[tid];
  }
}

// ---------------- pct = pc @ transform ----------------
__global__ void pct_kernel(const float* __restrict__ pc, const float* __restrict__ T, float* __restrict__ pct) {
  int id = blockIdx.x * 256 + threadIdx.x;
  if (id >= 8192) return;
  int b = id >> 11;
  const float* t = T + b * 9;
  float x = pc[id * 3 + 0], y = pc[id * 3 + 1], z = pc[id * 3 + 2];
  pct[id * 3 + 0] = x * t[0] + y * t[3] + z * t[6];
  pct[id * 3 + 1] = x * t[1] + y * t[4] + z * t[7];
  pct[id * 3 + 2] = x * t[2] + y * t[5] + z * t[8];
}

// ---------------- dense stats, C | 256 ----------------
__global__ __launch_bounds__(256) void dstats_kernel(const float* __restrict__ x, int total, int C,
                                                     double* __restrict__ acc) {
  __shared__ double dred[256];
  int tid = threadIdx.x;
  int c = tid % C;
  double ls = 0, lq = 0;
  int stride = gridDim.x << 8;
  for (int id = (blockIdx.x << 8) + tid; id < total; id += stride) {
    float v = x[id];
    ls += v; lq += (double)v * v;
  }
  dred[tid] = ls; __syncthreads();
  if (tid < C) { double v = 0; for (int i = tid; i < 256; i += C) v += dred[i]; atomicAdd(&acc[c], v); }
  __syncthreads();
  dred[tid] = lq; __syncthreads();
  if (tid < C) { double v = 0; for (int i = tid; i < 256; i += C) v += dred[i]; atomicAdd(&acc[C + c], v); }
}

// ---------------- stats for C=3 ----------------
__global__ __launch_bounds__(256) void stats3_kernel(const float* __restrict__ x, int total, double* __restrict__ acc) {
  __shared__ double dred[256];
  int tid = threadIdx.x;
  double ls[3] = {0, 0, 0}, lq[3] = {0, 0, 0};
  int stride = gridDim.x << 8;
  for (int id = (blockIdx.x << 8) + tid; id < total; id += stride) {
    float v = x[id];
    int c = id % 3;
    ls[c] += v; lq[c] += (double)v * v;
  }
  for (int cc = 0; cc < 3; ++cc) {
    __syncthreads();
    dred[tid] = ls[cc]; __syncthreads();
    for (int s = 128; s > 0; s >>= 1) { if (tid < s) dred[tid] += dred[tid + s]; __syncthreads(); }
    if (tid == 0) atomicAdd(&acc[cc], dred[0]);
    __syncthreads();
    dred[tid] = lq[cc]; __syncthreads();
    for (int s = 128; s > 0; s >>= 1) { if (tid < s) dred[tid] += dred[tid + s]; __syncthreads(); }
    if (tid == 0) atomicAdd(&acc[3 + cc], dred[0]);
  }
}

// ---------------- finalize: acc(sum,sumsq) -> (scale, shift) ----------------
__global__ void fin_kernel(const double* __restrict__ acc, const float* __restrict__ g, const float* __restrict__ bb,
                           double cnt, int C, float* __restrict__ sc) {
  int c = blockIdx.x * 256 + threadIdx.x;
  if (c >= C) return;
  double mean = acc[c] / cnt;
  double var = acc[C + c] / cnt - mean * mean;
  if (var < 0) var = 0;
  float inv = (float)(1.0 / sqrt(var + 1e-5));
  float s = g[c] * inv;
  sc[c] = s;
  sc[C + c] = bb[c] - (float)mean * s;
}

// ---------------- IF = [pct, bnlrelu(xo3T)] (B,N,67) ----------------
__global__ void if_kernel(const float* __restrict__ pct, const float* __restrict__ xo3T, const float* __restrict__ sc3,
                          float* __restrict__ IF) {
  int id = blockIdx.x * 256 + threadIdx.x;
  if (id >= 8192 * 67) return;
  int bn = id / 67, j = id % 67;
  float v;
  if (j < 3) v = pct[bn * 3 + j];
  else { int c = j - 3; v = lrelu(fmaf(xo3T[c * 8192 + bn], sc3[c], sc3[64 + c])); }
  IF[id] = v;
}

// ---------------- xt1 = IF @ w1(3x67)^T ----------------
__global__ void xt1_kernel(const float* __restrict__ IF, const float* __restrict__ W, float* __restrict__ xt1) {
  int id = blockIdx.x * 256 + threadIdx.x;
  if (id >= 8192 * 3) return;
  int bn = id / 3, c = id % 3;
  const float* f = IF + bn * 67;
  const float* w = W + c * 67;
  float a = 0.f;
  for (int j = 0; j < 67; ++j) a += f[j] * w[j];
  xt1[id] = a;
}

__global__ void t1_kernel(const float* __restrict__ xt1, const float* __restrict__ sc, float* __restrict__ trans1) {
  int id = blockIdx.x * 256 + threadIdx.x;
  if (id >= 24576) return;
  int c = id % 3;
  trans1[id] = lrelu(fmaf(xt1[id], sc[c], sc[3 + c]));
}

// ---------------- x2 = edgefeat(IF,134) @ w2(16x134)^T, store + stats ----------------
__global__ __launch_bounds__(256) void x2_kernel(const float* __restrict__ IF, const int* __restrict__ idx,
                                                 const float* __restrict__ W, float* __restrict__ x2,
                                                 double* __restrict__ acc) {
  __shared__ float WT[134 * 16];
  __shared__ double dred[256];
  int tid = threadIdx.x;
  for (int i = tid; i < 134 * 16; i += 256) { int c = i & 15, j = i >> 4; WT[j * 16 + c] = W[c * 134 + j]; }
  __syncthreads();
  int c = tid & 15;
  double ls = 0, lq = 0;
  const int total = 245760 * 16;
  int stride = gridDim.x << 8;
  for (int id = (blockIdx.x << 8) + tid; id < total; id += stride) {
    int p = id >> 4;
    int bn = p / 30; int b = bn >> 11;
    int nb = idx[p];
    const float* cen = IF + (size_t)bn * 67;
    const float* nbp = IF + (size_t)((b << 11) + nb) * 67;
    float a = 0.f;
    for (int j = 0; j < 67; ++j) {
      float cj = cen[j];
      a += cj * WT[j * 16 + c];
      a += (nbp[j] - cj) * WT[(67 + j) * 16 + c];
    }
    x2[id] = a;
    ls += a; lq += (double)a * a;
  }
  dred[tid] = ls; __syncthreads();
  if (tid < 16) { double v = 0; for (int i = tid; i < 256; i += 16) v += dred[i]; atomicAdd(&acc[tid], v); }
  __syncthreads();
  dred[tid] = lq; __syncthreads();
  if (tid < 16) { double v = 0; for (int i = tid; i < 256; i += 16) v += dred[i]; atomicAdd(&acc[16 + tid], v); }
}

// ---------------- out4=bnlrelu(x2); nm2/ne2 over K; x3 = [nm2,ne2] @ w3^T ----------------
__global__ __launch_bounds__(256) void k5_kernel(const float* __restrict__ x2, const float* __restrict__ sc2,
                                                 const float* __restrict__ W3, float* __restrict__ nm2,
                                                 float* __restrict__ ne2, float* __restrict__ x3) {
  __shared__ float W3T[32 * 16];
  __shared__ float o5[4][32];
  int tid = threadIdx.x;
  for (int i = tid; i < 512; i += 256) { int c = i & 15, j = i >> 4; W3T[j * 16 + c] = W3[c * 32 + j]; }
  __syncthreads();
  int lane = tid & 63, w = tid >> 6;
  int bn = blockIdx.x * 4 + w;
  int c = lane & 15, kq = lane >> 4;
  float s = sc2[c], t = sc2[16 + c];
  float lm = -3.4e38f, lsm = 0.f;
  const float* xp = x2 + (size_t)bn * 30 * 16;
  for (int k = kq; k < 30; k += 4) {
    float v = lrelu(fmaf(xp[k * 16 + c], s, t));
    lm = fmaxf(lm, v); lsm += v;
  }
  float lm2 = fmaxf(lm, __shfl_down(lm, 32, 64)); lm2 = fmaxf(lm2, __shfl_down(lm2, 16, 64));
  float ls2 = lsm + __shfl_down(lsm, 32, 64); ls2 = ls2 + __shfl_down(ls2, 16, 64);
  if (lane < 16) {
    float mean = ls2 / 30.f;
    nm2[bn * 16 + c] = lm2;
    ne2[bn * 16 + c] = mean;
    o5[w][c] = lm2; o5[w][16 + c] = mean;
  }
  __syncthreads();
  if (lane < 16) {
    float a = 0.f;
#pragma unroll
    for (int j = 0; j < 32; ++j) a += o5[w][j] * W3T[j * 16 + c];
    x3[bn * 16 + c] = a;
  }
}

// ---------------- final pack (4 identical graph copies) ----------------
__global__ void out_kernel(const float* __restrict__ x3, const float* __restrict__ sc3,
                           const float* __restrict__ nm2, const float* __restrict__ ne2,
                           float* __restrict__ out) {
  int id = blockIdx.x * 256 + threadIdx.x;
  if (id >= 4 * 16 * 2048) return;
  int n = id & 2047;
  int j = (id >> 11) & 15;
  int b = id >> 15;
  int bn = (b << 11) + n;
  float v5 = lrelu(fmaf(x3[bn * 16 + j], sc3[j], sc3[16 + j]));
  float vm = nm2[bn * 16 + j];
  float ve = ne2[bn * 16 + j];
#pragma unroll
  for (int g = 0; g < 4; ++g) {
    size_t base = (size_t)(b * 64 + g * 16 + j) * 2048 + n;
    out[base] = v5;
    out[524288 + base] = vm;
    out[1048576 + base] = ve;
  }
}

extern "C" void kernel_launch(void* const* d_in, const int* in_sizes, int n_in,
                              void* d_out, int out_size, void* d_ws, size_t ws_size,
                              hipStream_t stream) {
  (void)n_in; (void)out_size; (void)ws_size;
  const float* input_image = (const float*)d_in[0];
  bool dict = (in_sizes[10] == 384);
  int I_wo1, I_go1, I_bo1, I_wo2, I_go2, I_bo2, I_wo3, I_go3, I_bo3;
  int I_w1, I_g1, I_b1, I_w2, I_g2, I_b2, I_w3, I_g3, I_b3;
  int I_fc1w, I_fc1b, I_fc2w, I_fc2b, I_tw, I_tb;
  if (dict) {
    I_wo1 = 10; I_go1 = 11; I_bo1 = 12; I_wo2 = 13; I_go2 = 14; I_bo2 = 15;
    I_wo3 = 16; I_go3 = 17; I_bo3 = 18;
    I_w1 = 19; I_g1 = 20; I_b1 = 21; I_w2 = 22; I_g2 = 23; I_b2 = 24; I_w3 = 25; I_g3 = 26; I_b3 = 27;
    I_fc1w = 28; I_fc1b = 29; I_fc2w = 30; I_fc2b = 31; I_tw = 32; I_tb = 33;
  } else {
    I_fc1w = 10; I_fc1b = 11; I_fc2w = 12; I_fc2b = 13; I_tw = 14; I_tb = 15;
    I_wo1 = 16; I_go1 = 17; I_bo1 = 18; I_wo2 = 19; I_go2 = 20; I_bo2 = 21;
    I_wo3 = 22; I_go3 = 23; I_bo3 = 24;
    I_w1 = 25; I_g1 = 26; I_b1 = 27; I_w2 = 28; I_g2 = 29; I_b2 = 30; I_w3 = 31; I_g3 = 32; I_b3 = 33;
  }
#define FIN(i) ((const float*)d_in[i])
  float* ws = (float*)d_ws;
  float* pc      = ws;
  float* pct     = ws + 24576;
  float* trans1  = ws + 49152;
  int*   idx1    = (int*)(ws + 73728);
  int*   idx2    = (int*)(ws + 319488);
  int*   idx3    = (int*)(ws + 565248);
  float* m128b   = ws + 811008;                 // 8192*128
  float* catb    = ws + 1859584;                // 8192*128
  unsigned* maxmapb = (unsigned*)(ws + 2908160);// 4096
  unsigned* minmapb = (unsigned*)(ws + 2912256);// 4096
  float* m128mx  = ws + 2916352;                // 8192*128 pre-BN max
  float* m128mn  = ws + 3964928;                // 8192*128 pre-BN min
  float* gmaxb   = ws + 10248192;
  float* transf  = ws + 10252288;
  float* xo3T    = ws + 10252352;               // 64 x 8192
  float* IFb     = ws + 10776640;
  float* xt1b    = ws + 11325504;
  float* x2b     = ws + 11350080;
  float* nm2b    = ws + 15282240;
  float* ne2b    = ws + 15413312;
  float* x3b     = ws + 15544384;
  double* acc    = (double*)(ws + 15675456);    // 4096 doubles
  float* sc      = ws + 15683648;               // 4096 floats
  const double CNT_E = 245760.0, CNT_P = 8192.0;
  const int A64 = 0, A128 = 128, A1024 = 384, AO1 = 2432, AO2 = 2560, AO3 = 2688, AT1 = 2816, A2 = 2822, A3 = 2854;

  zero_kernel<<<32, 256, 0, stream>>>((float*)acc, 8192);
  iminit_kernel<<<16, 256, 0, stream>>>(maxmapb, minmapb);
  pc_kernel<<<96, 256, 0, stream>>>(input_image, pc);
  knn_kernel<<<2048, 256, 0, stream>>>(pc, idx1);
  mom6_kernel<<<32, 256, 0, stream>>>(pc, idx1, acc + A64);
  finE1_kernel<<<1, 64, 0, stream>>>(acc + A64, FIN(1), FIN(2), FIN(3), sc + A64);
  edgeA_kernel<<<1024, 256, 0, stream>>>(pc, idx1, FIN(1), sc + A64, FIN(4), m128mx, m128mn, acc + A128);
  fin_kernel<<<1, 256, 0, stream>>>(acc + A128, FIN(5), FIN(6), CNT_E, 128, sc + A128);
  applyA_kernel<<<4096, 256, 0, stream>>>(m128mx, m128mn, sc + A128, m128b);
  cmm1024_kernel<<<1024, 256, 0, stream>>>(m128b, FIN(7), acc + A1024, maxmapb, minmapb);
  fin1024_kernel<<<4, 256, 0, stream>>>(acc + A1024, FIN(8), FIN(9), maxmapb, minmapb, gmaxb);
  fc_kernel<<<4, 256, 0, stream>>>(gmaxb, FIN(I_fc1w), FIN(I_fc1b), FIN(I_fc2w), FIN(I_fc2b), FIN(I_tw), FIN(I_tb), transf);
  pct_kernel<<<32, 256, 0, stream>>>(pc, transf, pct);
  knn_kernel<<<2048, 256, 0, stream>>>(pct, idx2);
  mom6_kernel<<<32, 256, 0, stream>>>(pct, idx2, acc + AO1);
  finE1_kernel<<<1, 64, 0, stream>>>(acc + AO1, FIN(I_wo1), FIN(I_go1), FIN(I_bo1), sc + AO1);
  statsB_kernel<<<1024, 256, 0, stream>>>(pct, idx2, FIN(I_wo1), sc + AO1, FIN(I_wo2), acc + AO2);
  fin_kernel<<<1, 256, 0, stream>>>(acc + AO2, FIN(I_go2), FIN(I_bo2), CNT_E, 64, sc + AO2);
  poolB_kernel<<<1024, 256, 0, stream>>>(pct, idx2, FIN(I_wo1), sc + AO1, FIN(I_wo2), sc + AO2, catb);
  xo3g_kernel<<<128, 256, 0, stream>>>(catb, FIN(I_wo3), xo3T);
  rstats_kernel<<<64, 256, 0, stream>>>(xo3T, 8192, 64, acc + AO3);
  fin_kernel<<<1, 256, 0, stream>>>(acc + AO3, FIN(I_go3), FIN(I_bo3), CNT_P, 64, sc + AO3);
  if_kernel<<<2144, 256, 0, stream>>>(pct, xo3T, sc + AO3, IFb);
  xt1_kernel<<<96, 256, 0, stream>>>(IFb, FIN(I_w1), xt1b);
  stats3_kernel<<<32, 256, 0, stream>>>(xt1b, 24576, acc + AT1);
  fin_kernel<<<1, 256, 0, stream>>>(acc + AT1, FIN(I_g1), FIN(I_b1), CNT_P, 3, sc + AT1);
  t1_kernel<<<96, 256, 0, stream>>>(xt1b, sc + AT1, trans1);
  knn_kernel<<<2048, 256, 0, stream>>>(trans1, idx3);
  x2_kernel<<<512, 256, 0, stream>>>(IFb, idx3, FIN(I_w2), x2b, acc + A2);
  fin_kernel<<<1, 256, 0, stream>>>(acc + A2, FIN(I_g2), FIN(I_b2), CNT_E, 16, sc + A2);
  k5_kernel<<<2048, 256, 0, stream>>>(x2b, sc + A2, FIN(I_w3), nm2b, ne2b, x3b);
  dstats_kernel<<<256, 256, 0, stream>>>(x3b, 131072, 16, acc + A3);
  fin_kernel<<<1, 256, 0, stream>>>(acc + A3, FIN(I_g3), FIN(I_b3), CNT_P, 16, sc + A3);
  out_kernel<<<512, 256, 0, stream>>>(x3b, sc + A3, nm2b, ne2b, (float*)d_out);
#undef FIN
}

// Round 14
// 1178.864 us; speedup vs baseline: 1.9206x; 1.0601x over previous
//
#include <hip/hip_runtime.h>

// offset_deform: DGCNN-style forward. B=4, N=2048, K=30.
// NUM_GRAPH loop is iteration-invariant -> compute once, pack 4x.
// R14 (final): exact R10 source -- the verified optimum (1183us, absmax
// 0.1015625). Subsequent experiments (single-wave blocks R11/R12, q-loop
// unroll R13) all measured worse or neutral; reverting to the best point.

#define DEV __device__ __forceinline__
DEV float lrelu(float y) { return y > 0.f ? y : 0.2f * y; }
// monotone float->unsigned map (order-preserving for all finite floats)
DEV unsigned fmap(float x) {
  unsigned u = __float_as_uint(x);
  return (u & 0x80000000u) ? ~u : (u | 0x80000000u);
}
DEV float funmap(unsigned m) {
  unsigned u = (m & 0x80000000u) ? (m & 0x7FFFFFFFu) : ~m;
  return __uint_as_float(u);
}

// ---------------- utility ----------------
__global__ void zero_kernel(float* p, int n) {
  int id = blockIdx.x * 256 + threadIdx.x;
  if (id < n) p[id] = 0.f;
}

__global__ void iminit_kernel(unsigned* maxm, unsigned* minm) {
  int id = blockIdx.x * 256 + threadIdx.x;
  if (id < 4096) { maxm[id] = 0u; minm[id] = 0xFFFFFFFFu; }
}

// input (B,3,N) -> pc (B,N,3)
__global__ void pc_kernel(const float* __restrict__ in, float* __restrict__ pc) {
  int id = blockIdx.x * 256 + threadIdx.x;
  if (id >= 4 * 3 * 2048) return;
  int n = id & 2047;
  int c = (id >> 11) % 3;
  int b = id / (3 * 2048);
  pc[((b << 11) + n) * 3 + c] = in[id];
}

// ---------------- knn: wave per query point, per-lane top-4 list ----------------
// (known-good, absmax 0.1015625)
__global__ __launch_bounds__(256) void knn_kernel(const float* __restrict__ pts, int* __restrict__ idx_out) {
  int tid = threadIdx.x;
  int w = tid >> 6, lane = tid & 63;
  int bn = (blockIdx.x << 2) + w;
  int b = bn >> 11;
  const float* base = pts + (b << 11) * 3;
  double qx = pts[bn * 3 + 0], qy = pts[bn * 3 + 1], qz = pts[bn * 3 + 2];
  double sqn = qx * qx + qy * qy + qz * qz;
  double d[32];
#pragma unroll
  for (int i = 0; i < 32; ++i) {
    int m = lane + (i << 6);
    double px = base[m * 3 + 0], py = base[m * 3 + 1], pz = base[m * 3 + 2];
    double v = sqn - 2.0 * (qx * px + qy * py + qz * pz) + (px * px + py * py + pz * pz);
    d[i] = v;
  }
  unsigned used = 0u;
  double l0, l1, l2, l3; int p0, p1, p2, p3;
#define KNN_PASS(LV, PV)                                              \
  {                                                                   \
    double cm = 1e300; int cp = 0x7fffffff; int ci = 0;               \
    _Pragma("unroll")                                                 \
    for (int i = 0; i < 32; ++i) {                                    \
      double v = ((used >> i) & 1u) ? 1e300 : d[i];                   \
      if (v < cm) { cm = v; cp = lane + (i << 6); ci = i; }           \
    }                                                                 \
    used |= 1u << ci; LV = cm; PV = cp;                               \
  }
  KNN_PASS(l0, p0)
  KNN_PASS(l1, p1)
  KNN_PASS(l2, p2)
  KNN_PASS(l3, p3)
  int cnt = 4;
  int* out = idx_out + bn * 30;
  for (int it = 0; it < 30; ++it) {
    double gv = l0; int gp = p0;
#pragma unroll
    for (int off = 1; off < 64; off <<= 1) {
      double ov = __shfl_xor(gv, off, 64);
      int op = __shfl_xor(gp, off, 64);
      if (ov < gv || (ov == gv && op < gp)) { gv = ov; gp = op; }
    }
    if (lane == 0) out[it] = gp;
    if (lane == (gp & 63)) {          // owner: pop head
      l0 = l1; p0 = p1; l1 = l2; p1 = p2; l2 = l3; p2 = p3;
      l3 = 1e300; p3 = 0x7fffffff;
      cnt--;
      if (cnt == 0) {                 // rare: refill with true next-best
        KNN_PASS(l0, p0)
        cnt = 1;
      }
    }
  }
#undef KNN_PASS
}

// ---------------- mom6: S[6] + upper-tri M[21] of edge features ----------------
__global__ __launch_bounds__(256) void mom6_kernel(const float* __restrict__ pts, const int* __restrict__ idx,
                                                   double* __restrict__ acc) {
  __shared__ double sred[4][27];
  int tid = threadIdx.x;
  int lane = tid & 63, w = tid >> 6;
  double m[27];
#pragma unroll
  for (int i = 0; i < 27; ++i) m[i] = 0.0;
  int stride = gridDim.x << 8;
  for (int e = (blockIdx.x << 8) + tid; e < 245760; e += stride) {
    int bn = e / 30; int b = bn >> 11;
    int nb = idx[e];
    const float* cen = pts + bn * 3;
    const float* nbp = pts + ((b << 11) + nb) * 3;
    float f[6];
    f[0] = cen[0]; f[1] = cen[1]; f[2] = cen[2];
    f[3] = nbp[0] - f[0]; f[4] = nbp[1] - f[1]; f[5] = nbp[2] - f[2];
    int t = 6;
#pragma unroll
    for (int i = 0; i < 6; ++i) {
      m[i] += f[i];
#pragma unroll
      for (int j = i; j < 6; ++j) m[t++] += (double)f[i] * f[j];
    }
  }
#pragma unroll
  for (int i = 0; i < 27; ++i) {
    double v = m[i];
    v += __shfl_xor(v, 1, 64); v += __shfl_xor(v, 2, 64); v += __shfl_xor(v, 4, 64);
    v += __shfl_xor(v, 8, 64); v += __shfl_xor(v, 16, 64); v += __shfl_xor(v, 32, 64);
    m[i] = v;
  }
  if (lane == 0) {
#pragma unroll
    for (int i = 0; i < 27; ++i) sred[w][i] = m[i];
  }
  __syncthreads();
  if (tid < 27) atomicAdd(&acc[tid], sred[0][tid] + sred[1][tid] + sred[2][tid] + sred[3][tid]);
}

// finE1: per-channel mean/var from moment form  mean=w.S/E, E[x^2]=w^T M w / E
__global__ void finE1_kernel(const double* __restrict__ acc, const float* __restrict__ W,
                             const float* __restrict__ g, const float* __restrict__ bb,
                             float* __restrict__ sc) {
  int c = threadIdx.x;
  if (c >= 64) return;
  double wv[6];
#pragma unroll
  for (int i = 0; i < 6; ++i) wv[i] = W[c * 6 + i];
  double s = 0.0;
#pragma unroll
  for (int i = 0; i < 6; ++i) s += wv[i] * acc[i];
  double q = 0.0; int t = 6;
#pragma unroll
  for (int i = 0; i < 6; ++i)
#pragma unroll
    for (int j = i; j < 6; ++j) {
      double mm = acc[t++];
      q += (i == j) ? wv[i] * wv[i] * mm : 2.0 * wv[i] * wv[j] * mm;
    }
  const double E = 245760.0;
  double mean = s / E;
  double var = q / E - mean * mean;
  if (var < 0) var = 0;
  float sf = g[c] * (float)(1.0 / sqrt(var + 1e-5));
  sc[c] = sf;
  sc[64 + c] = bb[c] - (float)mean * sf;
}

// ---------------- edgeA: fused stats + pre-BN max/min pool (LDS XOR-swizzle) ----------------
// wave = 2 points, lane&31 = k. Phase1 (per chunk of 32 ch): lane writes its
// edge's channel-q value to slot k^q. Phase2: lane = (pt, ch) reads slot
// kk^ch. 40960 B LDS. Grid MUST be 1024.
__global__ __launch_bounds__(256) void edgeA_kernel(const float* __restrict__ pts, const int* __restrict__ idx,
                                                    const float* __restrict__ W1, const float* __restrict__ sc1,
                                                    const float* __restrict__ W2,
                                                    float* __restrict__ mxout, float* __restrict__ mnout,
                                                    double* __restrict__ acc) {
  __shared__ float vbuf[4][2][32][32];
  __shared__ double sred[4][32][8];
  int tid = threadIdx.x;
  int lane = tid & 63;
  int wv = tid >> 6;
  int k = lane & 31;
  int pt = lane >> 5;
  int bn = (blockIdx.x << 3) + (wv << 1) + pt;
  int b = bn >> 11;
  bool valid = k < 30;
  int nb = idx[bn * 30 + (valid ? k : 0)];
  const float* cen = pts + bn * 3;
  const float* nbp = pts + ((b << 11) + nb) * 3;
  float cx = cen[0], cy = cen[1], cz = cen[2];
  float dx = nbp[0] - cx, dy = nbp[1] - cy, dz = nbp[2] - cz;
  float y[64];
#pragma unroll
  for (int j = 0; j < 64; ++j) {
    float x = cx * W1[j * 6 + 0] + cy * W1[j * 6 + 1] + cz * W1[j * 6 + 2]
            + dx * W1[j * 6 + 3] + dy * W1[j * 6 + 4] + dz * W1[j * 6 + 5];
    y[j] = lrelu(fmaf(x, sc1[j], sc1[64 + j]));
  }
  int ch = lane & 31, pt2 = lane >> 5;
  int bn2 = (blockIdx.x << 3) + (wv << 1) + pt2;
  double aS[4] = {0, 0, 0, 0}, aQ[4] = {0, 0, 0, 0};
#pragma unroll
  for (int cc = 0; cc < 4; ++cc) {
    for (int q = 0; q < 32; ++q) {
      int c = cc * 32 + q;
      const float* w = W2 + c * 64;
      float a0 = 0.f, a1 = 0.f, a2 = 0.f, a3 = 0.f;
#pragma unroll
      for (int j = 0; j < 64; j += 4) {
        a0 = fmaf(y[j], w[j], a0); a1 = fmaf(y[j + 1], w[j + 1], a1);
        a2 = fmaf(y[j + 2], w[j + 2], a2); a3 = fmaf(y[j + 3], w[j + 3], a3);
      }
      vbuf[wv][pt][q][k ^ q] = (a0 + a1) + (a2 + a3);
    }
    __syncthreads();
    const float* vr = &vbuf[wv][pt2][ch][0];
    float v0 = vr[0 ^ ch];
    float mx = v0, mn = v0, sm = v0, qq = v0 * v0;
#pragma unroll
    for (int kkk = 1; kkk < 30; ++kkk) {
      float v = vr[kkk ^ ch];
      mx = fmaxf(mx, v); mn = fminf(mn, v);
      sm += v; qq = fmaf(v, v, qq);
    }
    mxout[bn2 * 128 + cc * 32 + ch] = mx;
    mnout[bn2 * 128 + cc * 32 + ch] = mn;
    float sm1 = __shfl_xor(sm, 32, 64);
    float qq1 = __shfl_xor(qq, 32, 64);
    if (lane < 32) { aS[cc] += (double)(sm + sm1); aQ[cc] += (double)(qq + qq1); }
    __syncthreads();
  }
  if (lane < 32) {
#pragma unroll
    for (int cc = 0; cc < 4; ++cc) { sred[wv][lane][cc * 2] = aS[cc]; sred[wv][lane][cc * 2 + 1] = aQ[cc]; }
  }
  __syncthreads();
  {
    int l = tid >> 3, j = tid & 7;
    double t = sred[0][l][j] + sred[1][l][j] + sred[2][l][j] + sred[3][l][j];
    int c = (j >> 1) * 32 + l;
    atomicAdd(&acc[(j & 1) * 128 + c], t);
  }
}

// applyA: m128[bn][c] = lrelu(s * (s>=0 ? mx : mn) + t)
__global__ void applyA_kernel(const float* __restrict__ mx, const float* __restrict__ mn,
                              const float* __restrict__ sc, float* __restrict__ m128) {
  int id = blockIdx.x * 256 + threadIdx.x;
  if (id >= 8192 * 128) return;
  int c = id & 127;
  float s = sc[c], t = sc[128 + c];
  float sel = (s >= 0.f) ? mx[id] : mn[id];
  m128[id] = lrelu(fmaf(sel, s, t));
}

// ---------------- statsB: sum/sumsq of x2 = bnlrelu(y) @ W2(64x64)^T (LDS XOR-swizzle) ----------------
// Grid MUST be 1024. 36864 B LDS.
__global__ __launch_bounds__(256) void statsB_kernel(const float* __restrict__ pts, const int* __restrict__ idx,
                                                     const float* __restrict__ W1, const float* __restrict__ sc1,
                                                     const float* __restrict__ W2, double* __restrict__ acc) {
  __shared__ float vbuf[4][2][32][32];
  __shared__ double sred[4][32][4];
  int tid = threadIdx.x;
  int lane = tid & 63;
  int wv = tid >> 6;
  int k = lane & 31;
  int pt = lane >> 5;
  int bn = (blockIdx.x << 3) + (wv << 1) + pt;
  int b = bn >> 11;
  bool valid = k < 30;
  int nb = idx[bn * 30 + (valid ? k : 0)];
  const float* cen = pts + bn * 3;
  const float* nbp = pts + ((b << 11) + nb) * 3;
  float cx = cen[0], cy = cen[1], cz = cen[2];
  float dx = nbp[0] - cx, dy = nbp[1] - cy, dz = nbp[2] - cz;
  float y[64];
#pragma unroll
  for (int j = 0; j < 64; ++j) {
    float x = cx * W1[j * 6 + 0] + cy * W1[j * 6 + 1] + cz * W1[j * 6 + 2]
            + dx * W1[j * 6 + 3] + dy * W1[j * 6 + 4] + dz * W1[j * 6 + 5];
    y[j] = lrelu(fmaf(x, sc1[j], sc1[64 + j]));
  }
  int ch = lane & 31, pt2 = lane >> 5;
  double aS[2] = {0, 0}, aQ[2] = {0, 0};
#pragma unroll
  for (int cc = 0; cc < 2; ++cc) {
    for (int q = 0; q < 32; ++q) {
      int c = cc * 32 + q;
      const float* w = W2 + c * 64;
      float a0 = 0.f, a1 = 0.f, a2 = 0.f, a3 = 0.f;
#pragma unroll
      for (int j = 0; j < 64; j += 4) {
        a0 = fmaf(y[j], w[j], a0); a1 = fmaf(y[j + 1], w[j + 1], a1);
        a2 = fmaf(y[j + 2], w[j + 2], a2); a3 = fmaf(y[j + 3], w[j + 3], a3);
      }
      vbuf[wv][pt][q][k ^ q] = (a0 + a1) + (a2 + a3);
    }
    __syncthreads();
    const float* vr = &vbuf[wv][pt2][ch][0];
    float v0 = vr[0 ^ ch];
    float sm = v0, qq = v0 * v0;
#pragma unroll
    for (int kkk = 1; kkk < 30; ++kkk) {
      float v = vr[kkk ^ ch];
      sm += v; qq = fmaf(v, v, qq);
    }
    float sm1 = __shfl_xor(sm, 32, 64);
    float qq1 = __shfl_xor(qq, 32, 64);
    if (lane < 32) { aS[cc] += (double)(sm + sm1); aQ[cc] += (double)(qq + qq1); }
    __syncthreads();
  }
  if (lane < 32) {
#pragma unroll
    for (int cc = 0; cc < 2; ++cc) { sred[wv][lane][cc * 2] = aS[cc]; sred[wv][lane][cc * 2 + 1] = aQ[cc]; }
  }
  __syncthreads();
  if (tid < 128) {
    int l = tid >> 2, j = tid & 3;
    double t = sred[0][l][j] + sred[1][l][j] + sred[2][l][j] + sred[3][l][j];
    int c = (j >> 1) * 32 + l;
    atomicAdd(&acc[(j & 1) * 64 + c], t);
  }
}

// ---------------- poolB: cat = [max_k v, mean_k v], v = bnlrelu(x2) (LDS XOR-swizzle) ----------------
// Grid MUST be 1024. 32768 B LDS.
__global__ __launch_bounds__(256) void poolB_kernel(const float* __restrict__ pts, const int* __restrict__ idx,
                                                    const float* __restrict__ W1, const float* __restrict__ sc1,
                                                    const float* __restrict__ W2, const float* __restrict__ sc2,
                                                    float* __restrict__ cat) {
  __shared__ float vbuf[4][2][32][32];
  int tid = threadIdx.x;
  int lane = tid & 63;
  int wv = tid >> 6;
  int k = lane & 31;
  int pt = lane >> 5;
  int bn = (blockIdx.x << 3) + (wv << 1) + pt;
  int b = bn >> 11;
  bool valid = k < 30;
  int nb = idx[bn * 30 + (valid ? k : 0)];
  const float* cen = pts + bn * 3;
  const float* nbp = pts + ((b << 11) + nb) * 3;
  float cx = cen[0], cy = cen[1], cz = cen[2];
  float dx = nbp[0] - cx, dy = nbp[1] - cy, dz = nbp[2] - cz;
  float y[64];
#pragma unroll
  for (int j = 0; j < 64; ++j) {
    float x = cx * W1[j * 6 + 0] + cy * W1[j * 6 + 1] + cz * W1[j * 6 + 2]
            + dx * W1[j * 6 + 3] + dy * W1[j * 6 + 4] + dz * W1[j * 6 + 5];
    y[j] = lrelu(fmaf(x, sc1[j], sc1[64 + j]));
  }
  int ch = lane & 31, pt2 = lane >> 5;
  int bn2 = (blockIdx.x << 3) + (wv << 1) + pt2;
#pragma unroll
  for (int cc = 0; cc < 2; ++cc) {
    for (int q = 0; q < 32; ++q) {
      int c = cc * 32 + q;
      const float* w = W2 + c * 64;
      float a0 = 0.f, a1 = 0.f, a2 = 0.f, a3 = 0.f;
#pragma unroll
      for (int j = 0; j < 64; j += 4) {
        a0 = fmaf(y[j], w[j], a0); a1 = fmaf(y[j + 1], w[j + 1], a1);
        a2 = fmaf(y[j + 2], w[j + 2], a2); a3 = fmaf(y[j + 3], w[j + 3], a3);
      }
      vbuf[wv][pt][q][k ^ q] = (a0 + a1) + (a2 + a3);
    }
    __syncthreads();
    int c2 = cc * 32 + ch;
    float s = sc2[c2], t = sc2[64 + c2];
    const float* vr = &vbuf[wv][pt2][ch][0];
    float v0 = lrelu(fmaf(vr[0 ^ ch], s, t));
    float mx = v0, sm = v0;
#pragma unroll
    for (int kkk = 1; kkk < 30; ++kkk) {
      float v = lrelu(fmaf(vr[kkk ^ ch], s, t));
      mx = fmaxf(mx, v); sm += v;
    }
    cat[bn2 * 128 + cc * 32 + ch] = mx;
    cat[bn2 * 128 + 64 + cc * 32 + ch] = sm * (1.f / 30.f);
    __syncthreads();
  }
}

// ---------------- xo3T[c][bn] = cat[bn][:] @ wo3[c][:] ----------------
__global__ __launch_bounds__(256) void xo3g_kernel(const float* __restrict__ cat, const float* __restrict__ W3,
                                                   float* __restrict__ xo3T) {
  int tid = threadIdx.x;
  int lane = tid & 63, cw = tid >> 6;
  int bn = (blockIdx.x << 6) + lane;
  const float* cr = cat + bn * 128;
  float a[16];
#pragma unroll
  for (int q = 0; q < 16; ++q) a[q] = 0.f;
  for (int j = 0; j < 128; ++j) {
    float v = cr[j];
#pragma unroll
    for (int q = 0; q < 16; ++q) a[q] += v * W3[(cw * 16 + q) * 128 + j];
  }
#pragma unroll
  for (int q = 0; q < 16; ++q) xo3T[(cw * 16 + q) * 8192 + bn] = a[q];
}

// ---------------- row stats: x is [C][E], one block per row ----------------
__global__ __launch_bounds__(256) void rstats_kernel(const float* __restrict__ x, int E, int C,
                                                     double* __restrict__ acc) {
  __shared__ double rd[256];
  int c = blockIdx.x, tid = threadIdx.x;
  const float* r = x + (size_t)c * E;
  double ls = 0, lq = 0;
  for (int i = tid; i < E; i += 256) { float v = r[i]; ls += v; lq += (double)v * v; }
  rd[tid] = ls; __syncthreads();
  for (int s = 128; s > 0; s >>= 1) { if (tid < s) rd[tid] += rd[tid + s]; __syncthreads(); }
  if (tid == 0) acc[c] = rd[0];
  __syncthreads();
  rd[tid] = lq; __syncthreads();
  for (int s = 128; s > 0; s >>= 1) { if (tid < s) rd[tid] += rd[tid + s]; __syncthreads(); }
  if (tid == 0) acc[C + c] = rd[0];
}

// ---------------- cmm1024: x=m128@W^T fused with {sum,sumsq,max,min} ----------------
__global__ __launch_bounds__(256) void cmm1024_kernel(const float* __restrict__ m128, const float* __restrict__ W,
                                                      double* __restrict__ acc, unsigned* __restrict__ maxm,
                                                      unsigned* __restrict__ minm) {
  __shared__ float mt[64 * 132];
  int tid = threadIdx.x;
  int lane = tid & 63;
  int b = blockIdx.x >> 8;
  int cg = (blockIdx.x >> 2) & 63;
  int ns = blockIdx.x & 3;
  int wu = __builtin_amdgcn_readfirstlane(tid >> 6);
  int cbase = cg * 16 + wu * 4;
  const float* wr = W + (size_t)cbase * 128;
  double ls[4] = {0, 0, 0, 0}, lq[4] = {0, 0, 0, 0};
  float mx[4], mn[4];
#pragma unroll
  for (int q = 0; q < 4; ++q) { mx[q] = -3.4e38f; mn[q] = 3.4e38f; }
  for (int ch = 0; ch < 8; ++ch) {
    int n0 = (ns << 9) + (ch << 6);
    __syncthreads();
    for (int i = tid; i < 2048; i += 256) {
      int r = i >> 5, jj = (i & 31) << 2;
      *(float4*)&mt[r * 132 + jj] = *(const float4*)&m128[(size_t)((b << 11) + n0 + r) * 128 + jj];
    }
    __syncthreads();
    float a[4] = {0.f, 0.f, 0.f, 0.f};
    const float* mrow = &mt[lane * 132];
#pragma unroll
    for (int j = 0; j < 128; j += 4) {
      float4 mv = *(const float4*)&mrow[j];
#pragma unroll
      for (int q = 0; q < 4; ++q) {
        const float* wq = wr + q * 128 + j;
        a[q] = fmaf(mv.x, wq[0], a[q]);
        a[q] = fmaf(mv.y, wq[1], a[q]);
        a[q] = fmaf(mv.z, wq[2], a[q]);
        a[q] = fmaf(mv.w, wq[3], a[q]);
      }
    }
#pragma unroll
    for (int q = 0; q < 4; ++q) {
      ls[q] += a[q]; lq[q] += (double)a[q] * a[q];
      mx[q] = fmaxf(mx[q], a[q]); mn[q] = fminf(mn[q], a[q]);
    }
  }
#pragma unroll
  for (int q = 0; q < 4; ++q) {
    double s = ls[q], sq = lq[q];
    float xm = mx[q], xn = mn[q];
    for (int off = 1; off < 64; off <<= 1) {
      s += __shfl_xor(s, off, 64);
      sq += __shfl_xor(sq, off, 64);
      xm = fmaxf(xm, __shfl_xor(xm, off, 64));
      xn = fminf(xn, __shfl_xor(xn, off, 64));
    }
    if (lane == 0) {
      int c = cbase + q;
      atomicAdd(&acc[c], s);
      atomicAdd(&acc[1024 + c], sq);
      atomicMax(&maxm[(b << 10) + c], fmap(xm));
      atomicMin(&minm[(b << 10) + c], fmap(xn));
    }
  }
}

// fin1024: stats -> (s,t); gmax = lrelu(s*extreme + t), extreme by sign(s)
__global__ void fin1024_kernel(const double* __restrict__ acc, const float* __restrict__ g,
                               const float* __restrict__ bb, const unsigned* __restrict__ maxm,
                               const unsigned* __restrict__ minm, float* __restrict__ gmax) {
  int c = blockIdx.x * 256 + threadIdx.x;
  if (c >= 1024) return;
  double mean = acc[c] / 8192.0;
  double var = acc[1024 + c] / 8192.0 - mean * mean;
  if (var < 0) var = 0;
  float s = g[c] * (float)(1.0 / sqrt(var + 1e-5));
  float t = bb[c] - (float)mean * s;
  for (int b = 0; b < 4; ++b) {
    float xm = (s >= 0.f) ? funmap(maxm[(b << 10) + c]) : funmap(minm[(b << 10) + c]);
    gmax[(b << 10) + c] = lrelu(fmaf(xm, s, t));
  }
}

// ---------------- fc1 -> fc2 -> transform (B,9) ----------------
__global__ __launch_bounds__(256) void fc_kernel(const float* __restrict__ gmax,
                                                 const float* __restrict__ fc1w, const float* __restrict__ fc1b,
                                                 const float* __restrict__ fc2w, const float* __restrict__ fc2b,
                                                 const float* __restrict__ tw, const float* __restrict__ tb,
                                                 float* __restrict__ transform) {
  __shared__ float net[1024];
  __shared__ float h1[512];
  __shared__ float h2[256];
  int b = blockIdx.x, tid = threadIdx.x;
  for (int i = tid; i < 1024; i += 256) net[i] = gmax[b * 1024 + i];
  __syncthreads();
  for (int o = tid; o < 512; o += 256) {
    float a = fc1b[o];
    const float* w = fc1w + o * 1024;
    for (int j = 0; j < 1024; ++j) a += net[j] * w[j];
    h1[o] = a;
  }
  __syncthreads();
  {
    int o = tid;
    float a = fc2b[o];
    const float* w = fc2w + o * 512;
    for (int j = 0; j < 512; ++j) a += h1[j] * w[j];
    h2[o] = a;
  }
  __syncthreads();
  if (tid < 9) {
    float a = 0.f;
    for (int i = 0; i < 256; ++i) a += h2[i] * tw[i * 9 + tid];
    float eye = (tid == 0 || tid == 4 || tid == 8) ? 1.f : 0.f;
    transform[b * 9 + tid] = a + eye + tb[tid];
  }
}

// ---------------- pct = pc @ transform ----------------
__global__ void pct_kernel(const float* __restrict__ pc, const float* __restrict__ T, float* __restrict__ pct) {
  int id = blockIdx.x * 256 + threadIdx.x;
  if (id >= 8192) return;
  int b = id >> 11;
  const float* t = T + b * 9;
  float x = pc[id * 3 + 0], y = pc[id * 3 + 1], z = pc[id * 3 + 2];
  pct[id * 3 + 0] = x * t[0] + y * t[3] + z * t[6];
  pct[id * 3 + 1] = x * t[1] + y * t[4] + z * t[7];
  pct[id * 3 + 2] = x * t[2] + y * t[5] + z * t[8];
}

// ---------------- dense stats, C | 256 ----------------
__global__ __launch_bounds__(256) void dstats_kernel(const float* __restrict__ x, int total, int C,
                                                     double* __restrict__ acc) {
  __shared__ double dred[256];
  int tid = threadIdx.x;
  int c = tid % C;
  double ls = 0, lq = 0;
  int stride = gridDim.x << 8;
  for (int id = (blockIdx.x << 8) + tid; id < total; id += stride) {
    float v = x[id];
    ls += v; lq += (double)v * v;
  }
  dred[tid] = ls; __syncthreads();
  if (tid < C) { double v = 0; for (int i = tid; i < 256; i += C) v += dred[i]; atomicAdd(&acc[c], v); }
  __syncthreads();
  dred[tid] = lq; __syncthreads();
  if (tid < C) { double v = 0; for (int i = tid; i < 256; i += C) v += dred[i]; atomicAdd(&acc[C + c], v); }
}

// ---------------- stats for C=3 ----------------
__global__ __launch_bounds__(256) void stats3_kernel(const float* __restrict__ x, int total, double* __restrict__ acc) {
  __shared__ double dred[256];
  int tid = threadIdx.x;
  double ls[3] = {0, 0, 0}, lq[3] = {0, 0, 0};
  int stride = gridDim.x << 8;
  for (int id = (blockIdx.x << 8) + tid; id < total; id += stride) {
    float v = x[id];
    int c = id % 3;
    ls[c] += v; lq[c] += (double)v * v;
  }
  for (int cc = 0; cc < 3; ++cc) {
    __syncthreads();
    dred[tid] = ls[cc]; __syncthreads();
    for (int s = 128; s > 0; s >>= 1) { if (tid < s) dred[tid] += dred[tid + s]; __syncthreads(); }
    if (tid == 0) atomicAdd(&acc[cc], dred[0]);
    __syncthreads();
    dred[tid] = lq[cc]; __syncthreads();
    for (int s = 128; s > 0; s >>= 1) { if (tid < s) dred[tid] += dred[tid + s]; __syncthreads(); }
    if (tid == 0) atomicAdd(&acc[3 + cc], dred[0]);
  }
}

// ---------------- finalize: acc(sum,sumsq) -> (scale, shift) ----------------
__global__ void fin_kernel(const double* __restrict__ acc, const float* __restrict__ g, const float* __restrict__ bb,
                           double cnt, int C, float* __restrict__ sc) {
  int c = blockIdx.x * 256 + threadIdx.x;
  if (c >= C) return;
  double mean = acc[c] / cnt;
  double var = acc[C + c] / cnt - mean * mean;
  if (var < 0) var = 0;
  float inv = (float)(1.0 / sqrt(var + 1e-5));
  float s = g[c] * inv;
  sc[c] = s;
  sc[C + c] = bb[c] - (float)mean * s;
}

// ---------------- IF = [pct, bnlrelu(xo3T)] (B,N,67) ----------------
__global__ void if_kernel(const float* __restrict__ pct, const float* __restrict__ xo3T, const float* __restrict__ sc3,
                          float* __restrict__ IF) {
  int id = blockIdx.x * 256 + threadIdx.x;
  if (id >= 8192 * 67) return;
  int bn = id / 67, j = id % 67;
  float v;
  if (j < 3) v = pct[bn * 3 + j];
  else { int c = j - 3; v = lrelu(fmaf(xo3T[c * 8192 + bn], sc3[c], sc3[64 + c])); }
  IF[id] = v;
}

// ---------------- xt1 = IF @ w1(3x67)^T ----------------
__global__ void xt1_kernel(const float* __restrict__ IF, const float* __restrict__ W, float* __restrict__ xt1) {
  int id = blockIdx.x * 256 + threadIdx.x;
  if (id >= 8192 * 3) return;
  int bn = id / 3, c = id % 3;
  const float* f = IF + bn * 67;
  const float* w = W + c * 67;
  float a = 0.f;
  for (int j = 0; j < 67; ++j) a += f[j] * w[j];
  xt1[id] = a;
}

__global__ void t1_kernel(const float* __restrict__ xt1, const float* __restrict__ sc, float* __restrict__ trans1) {
  int id = blockIdx.x * 256 + threadIdx.x;
  if (id >= 24576) return;
  int c = id % 3;
  trans1[id] = lrelu(fmaf(xt1[id], sc[c], sc[3 + c]));
}

// ---------------- x2 = edgefeat(IF,134) @ w2(16x134)^T, store + stats ----------------
__global__ __launch_bounds__(256) void x2_kernel(const float* __restrict__ IF, const int* __restrict__ idx,
                                                 const float* __restrict__ W, float* __restrict__ x2,
                                                 double* __restrict__ acc) {
  __shared__ float WT[134 * 16];
  __shared__ double dred[256];
  int tid = threadIdx.x;
  for (int i = tid; i < 134 * 16; i += 256) { int c = i & 15, j = i >> 4; WT[j * 16 + c] = W[c * 134 + j]; }
  __syncthreads();
  int c = tid & 15;
  double ls = 0, lq = 0;
  const int total = 245760 * 16;
  int stride = gridDim.x << 8;
  for (int id = (blockIdx.x << 8) + tid; id < total; id += stride) {
    int p = id >> 4;
    int bn = p / 30; int b = bn >> 11;
    int nb = idx[p];
    const float* cen = IF + (size_t)bn * 67;
    const float* nbp = IF + (size_t)((b << 11) + nb) * 67;
    float a = 0.f;
    for (int j = 0; j < 67; ++j) {
      float cj = cen[j];
      a += cj * WT[j * 16 + c];
      a += (nbp[j] - cj) * WT[(67 + j) * 16 + c];
    }
    x2[id] = a;
    ls += a; lq += (double)a * a;
  }
  dred[tid] = ls; __syncthreads();
  if (tid < 16) { double v = 0; for (int i = tid; i < 256; i += 16) v += dred[i]; atomicAdd(&acc[tid], v); }
  __syncthreads();
  dred[tid] = lq; __syncthreads();
  if (tid < 16) { double v = 0; for (int i = tid; i < 256; i += 16) v += dred[i]; atomicAdd(&acc[16 + tid], v); }
}

// ---------------- out4=bnlrelu(x2); nm2/ne2 over K; x3 = [nm2,ne2] @ w3^T ----------------
__global__ __launch_bounds__(256) void k5_kernel(const float* __restrict__ x2, const float* __restrict__ sc2,
                                                 const float* __restrict__ W3, float* __restrict__ nm2,
                                                 float* __restrict__ ne2, float* __restrict__ x3) {
  __shared__ float W3T[32 * 16];
  __shared__ float o5[4][32];
  int tid = threadIdx.x;
  for (int i = tid; i < 512; i += 256) { int c = i & 15, j = i >> 4; W3T[j * 16 + c] = W3[c * 32 + j]; }
  __syncthreads();
  int lane = tid & 63, w = tid >> 6;
  int bn = blockIdx.x * 4 + w;
  int c = lane & 15, kq = lane >> 4;
  float s = sc2[c], t = sc2[16 + c];
  float lm = -3.4e38f, lsm = 0.f;
  const float* xp = x2 + (size_t)bn * 30 * 16;
  for (int k = kq; k < 30; k += 4) {
    float v = lrelu(fmaf(xp[k * 16 + c], s, t));
    lm = fmaxf(lm, v); lsm += v;
  }
  float lm2 = fmaxf(lm, __shfl_down(lm, 32, 64)); lm2 = fmaxf(lm2, __shfl_down(lm2, 16, 64));
  float ls2 = lsm + __shfl_down(lsm, 32, 64); ls2 = ls2 + __shfl_down(ls2, 16, 64);
  if (lane < 16) {
    float mean = ls2 / 30.f;
    nm2[bn * 16 + c] = lm2;
    ne2[bn * 16 + c] = mean;
    o5[w][c] = lm2; o5[w][16 + c] = mean;
  }
  __syncthreads();
  if (lane < 16) {
    float a = 0.f;
#pragma unroll
    for (int j = 0; j < 32; ++j) a += o5[w][j] * W3T[j * 16 + c];
    x3[bn * 16 + c] = a;
  }
}

// ---------------- final pack (4 identical graph copies) ----------------
__global__ void out_kernel(const float* __restrict__ x3, const float* __restrict__ sc3,
                           const float* __restrict__ nm2, const float* __restrict__ ne2,
                           float* __restrict__ out) {
  int id = blockIdx.x * 256 + threadIdx.x;
  if (id >= 4 * 16 * 2048) return;
  int n = id & 2047;
  int j = (id >> 11) & 15;
  int b = id >> 15;
  int bn = (b << 11) + n;
  float v5 = lrelu(fmaf(x3[bn * 16 + j], sc3[j], sc3[16 + j]));
  float vm = nm2[bn * 16 + j];
  float ve = ne2[bn * 16 + j];
#pragma unroll
  for (int g = 0; g < 4; ++g) {
    size_t base = (size_t)(b * 64 + g * 16 + j) * 2048 + n;
    out[base] = v5;
    out[524288 + base] = vm;
    out[1048576 + base] = ve;
  }
}

extern "C" void kernel_launch(void* const* d_in, const int* in_sizes, int n_in,
                              void* d_out, int out_size, void* d_ws, size_t ws_size,
                              hipStream_t stream) {
  (void)n_in; (void)out_size; (void)ws_size;
  const float* input_image = (const float*)d_in[0];
  bool dict = (in_sizes[10] == 384);
  int I_wo1, I_go1, I_bo1, I_wo2, I_go2, I_bo2, I_wo3, I_go3, I_bo3;
  int I_w1, I_g1, I_b1, I_w2, I_g2, I_b2, I_w3, I_g3, I_b3;
  int I_fc1w, I_fc1b, I_fc2w, I_fc2b, I_tw, I_tb;
  if (dict) {
    I_wo1 = 10; I_go1 = 11; I_bo1 = 12; I_wo2 = 13; I_go2 = 14; I_bo2 = 15;
    I_wo3 = 16; I_go3 = 17; I_bo3 = 18;
    I_w1 = 19; I_g1 = 20; I_b1 = 21; I_w2 = 22; I_g2 = 23; I_b2 = 24; I_w3 = 25; I_g3 = 26; I_b3 = 27;
    I_fc1w = 28; I_fc1b = 29; I_fc2w = 30; I_fc2b = 31; I_tw = 32; I_tb = 33;
  } else {
    I_fc1w = 10; I_fc1b = 11; I_fc2w = 12; I_fc2b = 13; I_tw = 14; I_tb = 15;
    I_wo1 = 16; I_go1 = 17; I_bo1 = 18; I_wo2 = 19; I_go2 = 20; I_bo2 = 21;
    I_wo3 = 22; I_go3 = 23; I_bo3 = 24;
    I_w1 = 25; I_g1 = 26; I_b1 = 27; I_w2 = 28; I_g2 = 29; I_b2 = 30; I_w3 = 31; I_g3 = 32; I_b3 = 33;
  }
#define FIN(i) ((const float*)d_in[i])
  float* ws = (float*)d_ws;
  float* pc      = ws;
  float* pct     = ws + 24576;
  float* trans1  = ws + 49152;
  int*   idx1    = (int*)(ws + 73728);
  int*   idx2    = (int*)(ws + 319488);
  int*   idx3    = (int*)(ws + 565248);
  float* m128b   = ws + 811008;                 // 8192*128
  float* catb    = ws + 1859584;                // 8192*128
  unsigned* maxmapb = (unsigned*)(ws + 2908160);// 4096
  unsigned* minmapb = (unsigned*)(ws + 2912256);// 4096
  float* m128mx  = ws + 2916352;                // 8192*128 pre-BN max
  float* m128mn  = ws + 3964928;                // 8192*128 pre-BN min
  float* gmaxb   = ws + 10248192;
  float* transf  = ws + 10252288;
  float* xo3T    = ws + 10252352;               // 64 x 8192
  float* IFb     = ws + 10776640;
  float* xt1b    = ws + 11325504;
  float* x2b     = ws + 11350080;
  float* nm2b    = ws + 15282240;
  float* ne2b    = ws + 15413312;
  float* x3b     = ws + 15544384;
  double* acc    = (double*)(ws + 15675456);    // 4096 doubles
  float* sc      = ws + 15683648;               // 4096 floats
  const double CNT_E = 245760.0, CNT_P = 8192.0;
  const int A64 = 0, A128 = 128, A1024 = 384, AO1 = 2432, AO2 = 2560, AO3 = 2688, AT1 = 2816, A2 = 2822, A3 = 2854;

  zero_kernel<<<32, 256, 0, stream>>>((float*)acc, 8192);
  iminit_kernel<<<16, 256, 0, stream>>>(maxmapb, minmapb);
  pc_kernel<<<96, 256, 0, stream>>>(input_image, pc);
  knn_kernel<<<2048, 256, 0, stream>>>(pc, idx1);
  mom6_kernel<<<32, 256, 0, stream>>>(pc, idx1, acc + A64);
  finE1_kernel<<<1, 64, 0, stream>>>(acc + A64, FIN(1), FIN(2), FIN(3), sc + A64);
  edgeA_kernel<<<1024, 256, 0, stream>>>(pc, idx1, FIN(1), sc + A64, FIN(4), m128mx, m128mn, acc + A128);
  fin_kernel<<<1, 256, 0, stream>>>(acc + A128, FIN(5), FIN(6), CNT_E, 128, sc + A128);
  applyA_kernel<<<4096, 256, 0, stream>>>(m128mx, m128mn, sc + A128, m128b);
  cmm1024_kernel<<<1024, 256, 0, stream>>>(m128b, FIN(7), acc + A1024, maxmapb, minmapb);
  fin1024_kernel<<<4, 256, 0, stream>>>(acc + A1024, FIN(8), FIN(9), maxmapb, minmapb, gmaxb);
  fc_kernel<<<4, 256, 0, stream>>>(gmaxb, FIN(I_fc1w), FIN(I_fc1b), FIN(I_fc2w), FIN(I_fc2b), FIN(I_tw), FIN(I_tb), transf);
  pct_kernel<<<32, 256, 0, stream>>>(pc, transf, pct);
  knn_kernel<<<2048, 256, 0, stream>>>(pct, idx2);
  mom6_kernel<<<32, 256, 0, stream>>>(pct, idx2, acc + AO1);
  finE1_kernel<<<1, 64, 0, stream>>>(acc + AO1, FIN(I_wo1), FIN(I_go1), FIN(I_bo1), sc + AO1);
  statsB_kernel<<<1024, 256, 0, stream>>>(pct, idx2, FIN(I_wo1), sc + AO1, FIN(I_wo2), acc + AO2);
  fin_kernel<<<1, 256, 0, stream>>>(acc + AO2, FIN(I_go2), FIN(I_bo2), CNT_E, 64, sc + AO2);
  poolB_kernel<<<1024, 256, 0, stream>>>(pct, idx2, FIN(I_wo1), sc + AO1, FIN(I_wo2), sc + AO2, catb);
  xo3g_kernel<<<128, 256, 0, stream>>>(catb, FIN(I_wo3), xo3T);
  rstats_kernel<<<64, 256, 0, stream>>>(xo3T, 8192, 64, acc + AO3);
  fin_kernel<<<1, 256, 0, stream>>>(acc + AO3, FIN(I_go3), FIN(I_bo3), CNT_P, 64, sc + AO3);
  if_kernel<<<2144, 256, 0, stream>>>(pct, xo3T, sc + AO3, IFb);
  xt1_kernel<<<96, 256, 0, stream>>>(IFb, FIN(I_w1), xt1b);
  stats3_kernel<<<32, 256, 0, stream>>>(xt1b, 24576, acc + AT1);
  fin_kernel<<<1, 256, 0, stream>>>(acc + AT1, FIN(I_g1), FIN(I_b1), CNT_P, 3, sc + AT1);
  t1_kernel<<<96, 256, 0, stream>>>(xt1b, sc + AT1, trans1);
  knn_kernel<<<2048, 256, 0, stream>>>(trans1, idx3);
  x2_kernel<<<512, 256, 0, stream>>>(IFb, idx3, FIN(I_w2), x2b, acc + A2);
  fin_kernel<<<1, 256, 0, stream>>>(acc + A2, FIN(I_g2), FIN(I_b2), CNT_E, 16, sc + A2);
  k5_kernel<<<2048, 256, 0, stream>>>(x2b, sc + A2, FIN(I_w3), nm2b, ne2b, x3b);
  dstats_kernel<<<256, 256, 0, stream>>>(x3b, 131072, 16, acc + A3);
  fin_kernel<<<1, 256, 0, stream>>>(acc + A3, FIN(I_g3), FIN(I_b3), CNT_P, 16, sc + A3);
  out_kernel<<<512, 256, 0, stream>>>(x3b, sc + A3, nm2b, ne2b, (float*)d_out);
#undef FIN
}